// Round 10
// baseline (309.265 us; speedup 1.0000x reference)
//
#include <hip/hip_runtime.h>
#include <hip/hip_fp16.h>

#define N_NODES 50000
#define N_EDGES 1600000
#define F_IN 8
#define F_OUT 12
#define PERIODS 6
#define FP 48                      // F_IN * PERIODS
#define BKT_SH 7                   // 128 nodes per bucket
#define BKT_N 128
#define NBKT ((N_NODES + BKT_N - 1) / BKT_N)   // 391
#define CHK 4096
#define NCHK ((N_EDGES + CHK - 1) / CHK)       // 391
#define SEG_CAP 4736               // mean 4096, sigma ~64, +10 sigma
#define SRC_MASK 0x1FFFFu          // src < 50000 < 2^17

// ---- pass 1: per-chunk LDS histogram over buckets ----
__global__ void __launch_bounds__(256) k_hist(const int* __restrict__ dst,
                                              unsigned int* __restrict__ hist) {
    __shared__ unsigned int h[NBKT];
    int tid = threadIdx.x, blk = blockIdx.x;
    for (int k = tid; k < NBKT; k += 256) h[k] = 0u;
    __syncthreads();
    int base = blk * CHK;
    for (int i = tid; i < CHK; i += 256) {
        int e = base + i;
        if (e < N_EDGES) atomicAdd(&h[__builtin_nontemporal_load(&dst[e]) >> BKT_SH], 1u);
    }
    __syncthreads();
    for (int k = tid; k < NBKT; k += 256) hist[(size_t)blk * NBKT + k] = h[k];
}

// ---- pass 2a: per-bucket column exclusive scan over chunks, IN PLACE on hist ----
__global__ void __launch_bounds__(512) k_colscan(unsigned int* __restrict__ hist,
                                                 unsigned int* __restrict__ tot) {
    __shared__ unsigned int arr[512];
    int t = threadIdx.x, k = blockIdx.x;
    unsigned int v = (t < NCHK) ? hist[(size_t)t * NBKT + k] : 0u;
    arr[t] = v;
    __syncthreads();
    for (int off = 1; off < 512; off <<= 1) {
        unsigned int u = (t >= off) ? arr[t - off] : 0u;
        __syncthreads();
        arr[t] += u;
        __syncthreads();
    }
    if (t < NCHK) hist[(size_t)t * NBKT + k] = arr[t] - v;  // exclusive (colpre)
    if (t == NCHK - 1) tot[k] = arr[t];                     // bucket total
}

// ---- pass 2b: exclusive scan of bucket totals ----
__global__ void __launch_bounds__(512) k_topscan(const unsigned int* __restrict__ tot,
                                                 unsigned int* __restrict__ bktstart) {
    __shared__ unsigned int arr[512];
    int t = threadIdx.x;
    unsigned int v = (t < NBKT) ? tot[t] : 0u;
    arr[t] = v;
    __syncthreads();
    for (int off = 1; off < 512; off <<= 1) {
        unsigned int u = (t >= off) ? arr[t - off] : 0u;
        __syncthreads();
        arr[t] += u;
        __syncthreads();
    }
    if (t < NBKT) bktstart[t] = arr[t] - v;  // exclusive
    if (t == NBKT - 1) bktstart[NBKT] = arr[t];
}

// ---- pass 3: scatter edges to bucket segments; rank via LDS cursor atomics ----
// entry: hi32 = ew bits, lo32 = (d&127)<<24 | src
__global__ void __launch_bounds__(256) k_scatter(const int* __restrict__ src,
                                                 const int* __restrict__ dst,
                                                 const float* __restrict__ ew,
                                                 const unsigned int* __restrict__ colpre,
                                                 const unsigned int* __restrict__ bktstart,
                                                 unsigned long long* __restrict__ part) {
    __shared__ unsigned int ldsOff[NBKT];
    int tid = threadIdx.x, blk = blockIdx.x;
    for (int k = tid; k < NBKT; k += 256)
        ldsOff[k] = bktstart[k] + colpre[(size_t)blk * NBKT + k];
    __syncthreads();
    int base = blk * CHK;
    for (int i = tid; i < CHK; i += 256) {
        int e = base + i;
        if (e >= N_EDGES) continue;
        int s = __builtin_nontemporal_load(&src[e]);
        int d = __builtin_nontemporal_load(&dst[e]);
        float w = __builtin_nontemporal_load(&ew[e]);
        unsigned int pos = atomicAdd(&ldsOff[d >> BKT_SH], 1u);
        unsigned int lo = ((unsigned int)(d & (BKT_N - 1)) << 24) | (unsigned int)s;
        unsigned long long p = ((unsigned long long)__float_as_uint(w) << 32) | lo;
        __builtin_nontemporal_store(p, &part[pos]);
    }
}

// ---- pass 4: per-bucket LDS counting sort + deg/dinv + fp16 xs halves, fused ----
__global__ void __launch_bounds__(256) k_bucket(unsigned long long* __restrict__ part,
                                                const unsigned int* __restrict__ bktstart,
                                                const float* __restrict__ x,
                                                int* __restrict__ offs,
                                                float* __restrict__ dinv_g,
                                                uint2* __restrict__ xs_lo,
                                                uint2* __restrict__ xs_hi) {
    __shared__ uint2 stage[SEG_CAP];
    __shared__ unsigned int cnt[BKT_N], cnt2[BKT_N], rowstart[BKT_N], sc[BKT_N];
    __shared__ float degf[BKT_N], dinv_l[BKT_N];
    int tid = threadIdx.x, k = blockIdx.x;
    unsigned int base = bktstart[k];
    unsigned int m = bktstart[k + 1] - base;
    if (m > SEG_CAP) m = SEG_CAP;  // 10-sigma margin; memory safety only
    if (tid < BKT_N) { cnt[tid] = 0u; cnt2[tid] = 0u; degf[tid] = 1.0f; }  // self loop
    __syncthreads();
    for (unsigned int i = tid; i < m; i += 256) {
        unsigned long long p = __builtin_nontemporal_load(&part[base + i]);
        unsigned int lo = (unsigned int)p;
        unsigned int hi = (unsigned int)(p >> 32);
        stage[i] = make_uint2(lo, hi);
        unsigned int j = (lo >> 24) & (BKT_N - 1);
        atomicAdd(&cnt[j], 1u);
        atomicAdd(&degf[j], __uint_as_float(hi));
    }
    __syncthreads();
    if (tid < BKT_N) sc[tid] = cnt[tid];
    __syncthreads();
    for (int off = 1; off < BKT_N; off <<= 1) {
        unsigned int u = (tid >= (unsigned)off && tid < BKT_N) ? sc[tid - off] : 0u;
        __syncthreads();
        if (tid < BKT_N) sc[tid] += u;
        __syncthreads();
    }
    if (tid < BKT_N) rowstart[tid] = sc[tid] - cnt[tid];
    __syncthreads();

    int n0 = k * BKT_N;
    int nn = N_NODES - n0; if (nn > BKT_N) nn = BKT_N;

    if (tid < BKT_N) {
        float dv = rsqrtf(degf[tid]);
        dinv_l[tid] = dv;
        if (tid < nn) {
            dinv_g[n0 + tid] = dv;
            offs[n0 + tid] = (int)(base + rowstart[tid]);
        }
    }
    if (k == NBKT - 1 && tid == 0) offs[N_NODES] = N_EDGES;

    // sorted in-place write (reads from LDS stage — no hazard)
    for (unsigned int i = tid; i < m; i += 256) {
        uint2 v = stage[i];
        unsigned int j = (v.x >> 24) & (BKT_N - 1);
        unsigned int r = atomicAdd(&cnt2[j], 1u);
        unsigned long long p = ((unsigned long long)v.y << 32) | v.x;
        __builtin_nontemporal_store(p, &part[base + rowstart[j] + r]);
    }
    __syncthreads();

    // xs_lo/xs_hi[n*6+c] = fp16(dinv[n] * x[n, chunk]) — chunk i covers feats 4i..4i+3
    for (int idx = tid; idx < nn * 12; idx += 256) {
        int j = idx / 12, c = idx % 12;
        int n = n0 + j;
        float di = dinv_l[j];
        const float4* xr = (const float4*)(x + (size_t)n * FP + c * 4);
        float4 a = xr[0];
        __half2 h0 = __floats2half2_rn(di * a.x, di * a.y);
        __half2 h1 = __floats2half2_rn(di * a.z, di * a.w);
        uint2 o;
        o.x = *(unsigned int*)&h0; o.y = *(unsigned int*)&h1;
        if (c < 6) xs_lo[(size_t)n * 6 + c] = o;
        else       xs_hi[(size_t)n * 6 + (c - 6)] = o;
    }
}

// ---- pass 5 (x2): half-feature gather; xs_h (2.4 MB) stays L2-resident ----
// xagg[n, halfoff+c] = fp16( dinv[n] * (xs_h[n,c] + sum ew_e * xs_h[src_e,c]) )
__global__ void __launch_bounds__(256) k_gather(const uint2* __restrict__ xs_h,
                                                const float* __restrict__ dinv,
                                                const int* __restrict__ offs,
                                                const unsigned long long* __restrict__ part,
                                                uint2* __restrict__ xagg2,
                                                int halfoff) {
    int t = blockIdx.x * 256 + threadIdx.x;
    if (t >= N_NODES * 6) return;
    int n = t / 6, c = t % 6;
    uint2 self = xs_h[(size_t)n * 6 + c];
    float2 f0 = __half22float2(*(__half2*)&self.x);
    float2 f1 = __half22float2(*(__half2*)&self.y);
    float a0 = f0.x, a1 = f0.y, a2 = f1.x, a3 = f1.y;
    int b = offs[n], e = offs[n + 1];
    for (int kk = b; kk < e; kk++) {
        unsigned long long p = __builtin_nontemporal_load(&part[kk]);
        float w = __uint_as_float((unsigned int)(p >> 32));
        int s = (int)((unsigned int)p & SRC_MASK);
        uint2 v = xs_h[(size_t)s * 6 + c];
        float2 e0 = __half22float2(*(__half2*)&v.x);
        float2 e1 = __half22float2(*(__half2*)&v.y);
        a0 += w * e0.x; a1 += w * e0.y; a2 += w * e1.x; a3 += w * e1.y;
    }
    float di = dinv[n];
    __half2 o0 = __floats2half2_rn(di * a0, di * a1);
    __half2 o1 = __floats2half2_rn(di * a2, di * a3);
    uint2 o;
    o.x = *(unsigned int*)&o0; o.y = *(unsigned int*)&o1;
    xagg2[(size_t)n * 12 + halfoff + c] = o;
}

// ---- pass 6: per-node fused epilogue (gates + attention + relu + linear) ----
// H0 == 0 => R gate dead; Z/Ht use only first F_OUT cols of lzW/lhW.
__global__ void k_node(const uint2* __restrict__ xagg2, const float* __restrict__ att,
                       const float* __restrict__ Wz, const float* __restrict__ bz,
                       const float* __restrict__ Wh, const float* __restrict__ bh,
                       const float* __restrict__ lzW, const float* __restrict__ lzb,
                       const float* __restrict__ lhW, const float* __restrict__ lhb,
                       const float* __restrict__ linW, const float* __restrict__ linb,
                       float* __restrict__ out) {
    int n = blockIdx.x * blockDim.x + threadIdx.x;
    if (n >= N_NODES) return;

    float a[PERIODS];
    float m = -1e30f;
    #pragma unroll
    for (int p = 0; p < PERIODS; p++) { a[p] = att[p]; m = fmaxf(m, a[p]); }
    float se = 0.f;
    #pragma unroll
    for (int p = 0; p < PERIODS; p++) { a[p] = __expf(a[p] - m); se += a[p]; }
    float inv = 1.f / se;
    #pragma unroll
    for (int p = 0; p < PERIODS; p++) a[p] *= inv;

    float row[FP];
    const uint2* xr = xagg2 + (size_t)n * 12;
    #pragma unroll
    for (int i = 0; i < 12; i++) {
        uint2 v = xr[i];
        float2 f0 = __half22float2(*(__half2*)&v.x);
        float2 f1 = __half22float2(*(__half2*)&v.y);
        row[4 * i] = f0.x; row[4 * i + 1] = f0.y;
        row[4 * i + 2] = f1.x; row[4 * i + 3] = f1.y;
    }

    float H[F_OUT];
    #pragma unroll
    for (int j = 0; j < F_OUT; j++) H[j] = 0.f;

    for (int p = 0; p < PERIODS; p++) {
        float gz[F_OUT], gh[F_OUT];
        #pragma unroll
        for (int j = 0; j < F_OUT; j++) { gz[j] = bz[j]; gh[j] = bh[j]; }
        #pragma unroll
        for (int f = 0; f < F_IN; f++) {
            float xv = row[f * PERIODS + p];
            #pragma unroll
            for (int j = 0; j < F_OUT; j++) {
                gz[j] += xv * Wz[f * F_OUT + j];
                gh[j] += xv * Wh[f * F_OUT + j];
            }
        }
        #pragma unroll
        for (int j = 0; j < F_OUT; j++) {
            float z = lzb[j], t2 = lhb[j];
            #pragma unroll
            for (int kk = 0; kk < F_OUT; kk++) {
                z  += gz[kk] * lzW[j * (2 * F_OUT) + kk];
                t2 += gh[kk] * lhW[j * (2 * F_OUT) + kk];
            }
            float Z = 1.f / (1.f + __expf(-z));
            H[j] += a[p] * (1.f - Z) * tanhf(t2);
        }
    }

    float* op = out + (size_t)n * PERIODS;
    #pragma unroll
    for (int q = 0; q < PERIODS; q++) {
        float acc = linb[q];
        #pragma unroll
        for (int j = 0; j < F_OUT; j++)
            acc += fmaxf(H[j], 0.f) * linW[q * F_OUT + j];
        op[q] = acc;
    }
}

extern "C" void kernel_launch(void* const* d_in, const int* in_sizes, int n_in,
                              void* d_out, int out_size, void* d_ws, size_t ws_size,
                              hipStream_t stream) {
    const float* x    = (const float*)d_in[0];
    const int*   ei   = (const int*)d_in[1];
    const float* ew   = (const float*)d_in[2];
    const float* att  = (const float*)d_in[3];
    const float* Wz   = (const float*)d_in[4];
    const float* bz   = (const float*)d_in[5];
    // d_in[6]=Wr, d_in[7]=br : dead (H0 == 0)
    const float* Wh   = (const float*)d_in[8];
    const float* bh   = (const float*)d_in[9];
    const float* lzW  = (const float*)d_in[10];
    const float* lzb  = (const float*)d_in[11];
    // d_in[12]=lrW, d_in[13]=lrb : dead
    const float* lhW  = (const float*)d_in[14];
    const float* lhb  = (const float*)d_in[15];
    const float* linW = (const float*)d_in[16];
    const float* linb = (const float*)d_in[17];
    float* out = (float*)d_out;

    // ws layout (~23.4 MB): part, xs_lo, xs_hi (fp16 dinv*x halves), xagg (fp16),
    // hist (colpre in place), dinv, offs, bktstart, tot
    unsigned long long* part = (unsigned long long*)d_ws;            // E * 8B (sorted in place)
    uint2* xs_lo = (uint2*)(part + N_EDGES);                         // N*6 uint2 = 2.4 MB
    uint2* xs_hi = xs_lo + (size_t)N_NODES * 6;                      // N*6 uint2 = 2.4 MB
    uint2* xagg2 = xs_hi + (size_t)N_NODES * 6;                      // N*12 uint2 = 4.8 MB
    unsigned int* hist = (unsigned int*)(xagg2 + (size_t)N_NODES * 12); // NCHK*NBKT u32
    float* dinv = (float*)(hist + (size_t)NCHK * NBKT);              // N floats
    int*   offs = (int*)(dinv + N_NODES);                            // N+1 ints
    unsigned int* bktstart = (unsigned int*)(offs + N_NODES + 1);    // NBKT+1 u32
    unsigned int* tot = bktstart + NBKT + 1;                         // NBKT u32

    const int* srcp = ei;
    const int* dstp = ei + N_EDGES;

    k_hist<<<NCHK, 256, 0, stream>>>(dstp, hist);
    k_colscan<<<NBKT, 512, 0, stream>>>(hist, tot);
    k_topscan<<<1, 512, 0, stream>>>(tot, bktstart);
    k_scatter<<<NCHK, 256, 0, stream>>>(srcp, dstp, ew, hist, bktstart, part);
    k_bucket<<<NBKT, 256, 0, stream>>>(part, bktstart, x, offs, dinv, xs_lo, xs_hi);
    k_gather<<<(N_NODES * 6 + 255) / 256, 256, 0, stream>>>(xs_lo, dinv, offs, part, xagg2, 0);
    k_gather<<<(N_NODES * 6 + 255) / 256, 256, 0, stream>>>(xs_hi, dinv, offs, part, xagg2, 6);
    k_node<<<(N_NODES + 255) / 256, 256, 0, stream>>>(xagg2, att, Wz, bz, Wh, bh,
                                                      lzW, lzb, lhW, lhb, linW, linb, out);
}

// Round 11
// 247.691 us; speedup vs baseline: 1.2486x; 1.2486x over previous
//
#include <hip/hip_runtime.h>
#include <hip/hip_fp16.h>

#define N_NODES 50000
#define N_EDGES 1600000
#define F_IN 8
#define F_OUT 12
#define PERIODS 6
#define FP 48                      // F_IN * PERIODS
#define BKT_SH 7                   // 128 nodes per bucket
#define BKT_N 128
#define NBKT ((N_NODES + BKT_N - 1) / BKT_N)   // 391
#define CHK 4096
#define NCHK ((N_EDGES + CHK - 1) / CHK)       // 391
#define SEG_CAP 4736               // mean 4096, sigma ~64, +10 sigma
#define SRC_MASK 0x1FFFFu          // src < 50000 < 2^17

// ---- pass 1: per-chunk LDS histogram over buckets ----
__global__ void __launch_bounds__(256) k_hist(const int* __restrict__ dst,
                                              unsigned int* __restrict__ hist) {
    __shared__ unsigned int h[NBKT];
    int tid = threadIdx.x, blk = blockIdx.x;
    for (int k = tid; k < NBKT; k += 256) h[k] = 0u;
    __syncthreads();
    int base = blk * CHK;
    for (int i = tid; i < CHK; i += 256) {
        int e = base + i;
        if (e < N_EDGES) atomicAdd(&h[dst[e] >> BKT_SH], 1u);
    }
    __syncthreads();
    for (int k = tid; k < NBKT; k += 256) hist[(size_t)blk * NBKT + k] = h[k];
}

// ---- pass 2a: per-bucket column exclusive scan over chunks, IN PLACE on hist ----
__global__ void __launch_bounds__(512) k_colscan(unsigned int* __restrict__ hist,
                                                 unsigned int* __restrict__ tot) {
    __shared__ unsigned int arr[512];
    int t = threadIdx.x, k = blockIdx.x;
    unsigned int v = (t < NCHK) ? hist[(size_t)t * NBKT + k] : 0u;
    arr[t] = v;
    __syncthreads();
    for (int off = 1; off < 512; off <<= 1) {
        unsigned int u = (t >= off) ? arr[t - off] : 0u;
        __syncthreads();
        arr[t] += u;
        __syncthreads();
    }
    if (t < NCHK) hist[(size_t)t * NBKT + k] = arr[t] - v;  // exclusive (colpre)
    if (t == NCHK - 1) tot[k] = arr[t];                     // bucket total
}

// ---- pass 2b: exclusive scan of bucket totals ----
__global__ void __launch_bounds__(512) k_topscan(const unsigned int* __restrict__ tot,
                                                 unsigned int* __restrict__ bktstart) {
    __shared__ unsigned int arr[512];
    int t = threadIdx.x;
    unsigned int v = (t < NBKT) ? tot[t] : 0u;
    arr[t] = v;
    __syncthreads();
    for (int off = 1; off < 512; off <<= 1) {
        unsigned int u = (t >= off) ? arr[t - off] : 0u;
        __syncthreads();
        arr[t] += u;
        __syncthreads();
    }
    if (t < NBKT) bktstart[t] = arr[t] - v;  // exclusive
    if (t == NBKT - 1) bktstart[NBKT] = arr[t];
}

// ---- pass 3: scatter edges to bucket segments; rank via LDS cursor atomics ----
// entry: hi32 = ew bits, lo32 = (d&127)<<24 | src
__global__ void __launch_bounds__(256) k_scatter(const int* __restrict__ src,
                                                 const int* __restrict__ dst,
                                                 const float* __restrict__ ew,
                                                 const unsigned int* __restrict__ colpre,
                                                 const unsigned int* __restrict__ bktstart,
                                                 unsigned long long* __restrict__ part) {
    __shared__ unsigned int ldsOff[NBKT];
    int tid = threadIdx.x, blk = blockIdx.x;
    for (int k = tid; k < NBKT; k += 256)
        ldsOff[k] = bktstart[k] + colpre[(size_t)blk * NBKT + k];
    __syncthreads();
    int base = blk * CHK;
    for (int i = tid; i < CHK; i += 256) {
        int e = base + i;
        if (e >= N_EDGES) continue;
        int s = src[e], d = dst[e];
        unsigned int pos = atomicAdd(&ldsOff[d >> BKT_SH], 1u);
        unsigned int lo = ((unsigned int)(d & (BKT_N - 1)) << 24) | (unsigned int)s;
        part[pos] = ((unsigned long long)__float_as_uint(ew[e]) << 32) | lo;
    }
}

// ---- pass 4: per-bucket LDS counting sort + deg/dinv + fp16 xs halves, fused ----
__global__ void __launch_bounds__(256) k_bucket(unsigned long long* __restrict__ part,
                                                const unsigned int* __restrict__ bktstart,
                                                const float* __restrict__ x,
                                                int* __restrict__ offs,
                                                float* __restrict__ dinv_g,
                                                uint2* __restrict__ xs_lo,
                                                uint2* __restrict__ xs_hi) {
    __shared__ uint2 stage[SEG_CAP];
    __shared__ unsigned int cnt[BKT_N], cnt2[BKT_N], rowstart[BKT_N], sc[BKT_N];
    __shared__ float degf[BKT_N], dinv_l[BKT_N];
    int tid = threadIdx.x, k = blockIdx.x;
    unsigned int base = bktstart[k];
    unsigned int m = bktstart[k + 1] - base;
    if (m > SEG_CAP) m = SEG_CAP;  // 10-sigma margin; memory safety only
    if (tid < BKT_N) { cnt[tid] = 0u; cnt2[tid] = 0u; degf[tid] = 1.0f; }  // self loop
    __syncthreads();
    for (unsigned int i = tid; i < m; i += 256) {
        unsigned long long p = part[base + i];
        unsigned int lo = (unsigned int)p;
        unsigned int hi = (unsigned int)(p >> 32);
        stage[i] = make_uint2(lo, hi);
        unsigned int j = (lo >> 24) & (BKT_N - 1);
        atomicAdd(&cnt[j], 1u);
        atomicAdd(&degf[j], __uint_as_float(hi));
    }
    __syncthreads();
    if (tid < BKT_N) sc[tid] = cnt[tid];
    __syncthreads();
    for (int off = 1; off < BKT_N; off <<= 1) {
        unsigned int u = (tid >= (unsigned)off && tid < BKT_N) ? sc[tid - off] : 0u;
        __syncthreads();
        if (tid < BKT_N) sc[tid] += u;
        __syncthreads();
    }
    if (tid < BKT_N) rowstart[tid] = sc[tid] - cnt[tid];
    __syncthreads();

    int n0 = k * BKT_N;
    int nn = N_NODES - n0; if (nn > BKT_N) nn = BKT_N;

    if (tid < BKT_N) {
        float dv = rsqrtf(degf[tid]);
        dinv_l[tid] = dv;
        if (tid < nn) {
            dinv_g[n0 + tid] = dv;
            offs[n0 + tid] = (int)(base + rowstart[tid]);
        }
    }
    if (k == NBKT - 1 && tid == 0) offs[N_NODES] = N_EDGES;

    // sorted in-place write (reads from LDS stage — no hazard)
    for (unsigned int i = tid; i < m; i += 256) {
        uint2 v = stage[i];
        unsigned int j = (v.x >> 24) & (BKT_N - 1);
        unsigned int r = atomicAdd(&cnt2[j], 1u);
        part[base + rowstart[j] + r] = ((unsigned long long)v.y << 32) | v.x;
    }
    __syncthreads();

    // xs_lo/xs_hi[n*6+c] = fp16(dinv[n] * x[n, chunk]) — chunk c covers feats 4c..4c+3
    for (int idx = tid; idx < nn * 12; idx += 256) {
        int j = idx / 12, c = idx % 12;
        int n = n0 + j;
        float di = dinv_l[j];
        const float4* xr = (const float4*)(x + (size_t)n * FP + c * 4);
        float4 a = xr[0];
        __half2 h0 = __floats2half2_rn(di * a.x, di * a.y);
        __half2 h1 = __floats2half2_rn(di * a.z, di * a.w);
        uint2 o;
        o.x = *(unsigned int*)&h0; o.y = *(unsigned int*)&h1;
        if (c < 6) xs_lo[(size_t)n * 6 + c] = o;
        else       xs_hi[(size_t)n * 6 + (c - 6)] = o;
    }
}

// ---- pass 5 (x2): half-feature gather; xs_h (2.4 MB) stays L2-resident ----
// xagg[n, halfoff+c] = fp16( dinv[n] * (xs_h[n,c] + sum ew_e * xs_h[src_e,c]) )
__global__ void __launch_bounds__(256) k_gather(const uint2* __restrict__ xs_h,
                                                const float* __restrict__ dinv,
                                                const int* __restrict__ offs,
                                                const unsigned long long* __restrict__ part,
                                                uint2* __restrict__ xagg2,
                                                int halfoff) {
    int t = blockIdx.x * 256 + threadIdx.x;
    if (t >= N_NODES * 6) return;
    int n = t / 6, c = t % 6;
    uint2 self = xs_h[(size_t)n * 6 + c];
    float2 f0 = __half22float2(*(__half2*)&self.x);
    float2 f1 = __half22float2(*(__half2*)&self.y);
    float a0 = f0.x, a1 = f0.y, a2 = f1.x, a3 = f1.y;
    int b = offs[n], e = offs[n + 1];
    for (int kk = b; kk < e; kk++) {
        unsigned long long p = part[kk];
        float w = __uint_as_float((unsigned int)(p >> 32));
        int s = (int)((unsigned int)p & SRC_MASK);
        uint2 v = xs_h[(size_t)s * 6 + c];
        float2 e0 = __half22float2(*(__half2*)&v.x);
        float2 e1 = __half22float2(*(__half2*)&v.y);
        a0 += w * e0.x; a1 += w * e0.y; a2 += w * e1.x; a3 += w * e1.y;
    }
    float di = dinv[n];
    __half2 o0 = __floats2half2_rn(di * a0, di * a1);
    __half2 o1 = __floats2half2_rn(di * a2, di * a3);
    uint2 o;
    o.x = *(unsigned int*)&o0; o.y = *(unsigned int*)&o1;
    xagg2[(size_t)n * 12 + halfoff + c] = o;
}

// ---- pass 6: per-node fused epilogue (gates + attention + relu + linear) ----
// H0 == 0 => R gate dead; Z/Ht use only first F_OUT cols of lzW/lhW.
__global__ void k_node(const uint2* __restrict__ xagg2, const float* __restrict__ att,
                       const float* __restrict__ Wz, const float* __restrict__ bz,
                       const float* __restrict__ Wh, const float* __restrict__ bh,
                       const float* __restrict__ lzW, const float* __restrict__ lzb,
                       const float* __restrict__ lhW, const float* __restrict__ lhb,
                       const float* __restrict__ linW, const float* __restrict__ linb,
                       float* __restrict__ out) {
    int n = blockIdx.x * blockDim.x + threadIdx.x;
    if (n >= N_NODES) return;

    float a[PERIODS];
    float m = -1e30f;
    #pragma unroll
    for (int p = 0; p < PERIODS; p++) { a[p] = att[p]; m = fmaxf(m, a[p]); }
    float se = 0.f;
    #pragma unroll
    for (int p = 0; p < PERIODS; p++) { a[p] = __expf(a[p] - m); se += a[p]; }
    float inv = 1.f / se;
    #pragma unroll
    for (int p = 0; p < PERIODS; p++) a[p] *= inv;

    float row[FP];
    const uint2* xr = xagg2 + (size_t)n * 12;
    #pragma unroll
    for (int i = 0; i < 12; i++) {
        uint2 v = xr[i];
        float2 f0 = __half22float2(*(__half2*)&v.x);
        float2 f1 = __half22float2(*(__half2*)&v.y);
        row[4 * i] = f0.x; row[4 * i + 1] = f0.y;
        row[4 * i + 2] = f1.x; row[4 * i + 3] = f1.y;
    }

    float H[F_OUT];
    #pragma unroll
    for (int j = 0; j < F_OUT; j++) H[j] = 0.f;

    for (int p = 0; p < PERIODS; p++) {
        float gz[F_OUT], gh[F_OUT];
        #pragma unroll
        for (int j = 0; j < F_OUT; j++) { gz[j] = bz[j]; gh[j] = bh[j]; }
        #pragma unroll
        for (int f = 0; f < F_IN; f++) {
            float xv = row[f * PERIODS + p];
            #pragma unroll
            for (int j = 0; j < F_OUT; j++) {
                gz[j] += xv * Wz[f * F_OUT + j];
                gh[j] += xv * Wh[f * F_OUT + j];
            }
        }
        #pragma unroll
        for (int j = 0; j < F_OUT; j++) {
            float z = lzb[j], t2 = lhb[j];
            #pragma unroll
            for (int kk = 0; kk < F_OUT; kk++) {
                z  += gz[kk] * lzW[j * (2 * F_OUT) + kk];
                t2 += gh[kk] * lhW[j * (2 * F_OUT) + kk];
            }
            float Z = 1.f / (1.f + __expf(-z));
            H[j] += a[p] * (1.f - Z) * tanhf(t2);
        }
    }

    float* op = out + (size_t)n * PERIODS;
    #pragma unroll
    for (int q = 0; q < PERIODS; q++) {
        float acc = linb[q];
        #pragma unroll
        for (int j = 0; j < F_OUT; j++)
            acc += fmaxf(H[j], 0.f) * linW[q * F_OUT + j];
        op[q] = acc;
    }
}

extern "C" void kernel_launch(void* const* d_in, const int* in_sizes, int n_in,
                              void* d_out, int out_size, void* d_ws, size_t ws_size,
                              hipStream_t stream) {
    const float* x    = (const float*)d_in[0];
    const int*   ei   = (const int*)d_in[1];
    const float* ew   = (const float*)d_in[2];
    const float* att  = (const float*)d_in[3];
    const float* Wz   = (const float*)d_in[4];
    const float* bz   = (const float*)d_in[5];
    // d_in[6]=Wr, d_in[7]=br : dead (H0 == 0)
    const float* Wh   = (const float*)d_in[8];
    const float* bh   = (const float*)d_in[9];
    const float* lzW  = (const float*)d_in[10];
    const float* lzb  = (const float*)d_in[11];
    // d_in[12]=lrW, d_in[13]=lrb : dead
    const float* lhW  = (const float*)d_in[14];
    const float* lhb  = (const float*)d_in[15];
    const float* linW = (const float*)d_in[16];
    const float* linb = (const float*)d_in[17];
    float* out = (float*)d_out;

    // ws layout (~23.4 MB): part, xs_lo, xs_hi (fp16 dinv*x halves), xagg (fp16),
    // hist (colpre in place), dinv, offs, bktstart, tot
    unsigned long long* part = (unsigned long long*)d_ws;            // E * 8B (sorted in place)
    uint2* xs_lo = (uint2*)(part + N_EDGES);                         // N*6 uint2 = 2.4 MB
    uint2* xs_hi = xs_lo + (size_t)N_NODES * 6;                      // N*6 uint2 = 2.4 MB
    uint2* xagg2 = xs_hi + (size_t)N_NODES * 6;                      // N*12 uint2 = 4.8 MB
    unsigned int* hist = (unsigned int*)(xagg2 + (size_t)N_NODES * 12); // NCHK*NBKT u32
    float* dinv = (float*)(hist + (size_t)NCHK * NBKT);              // N floats
    int*   offs = (int*)(dinv + N_NODES);                            // N+1 ints
    unsigned int* bktstart = (unsigned int*)(offs + N_NODES + 1);    // NBKT+1 u32
    unsigned int* tot = bktstart + NBKT + 1;                         // NBKT u32

    const int* srcp = ei;
    const int* dstp = ei + N_EDGES;

    k_hist<<<NCHK, 256, 0, stream>>>(dstp, hist);
    k_colscan<<<NBKT, 512, 0, stream>>>(hist, tot);
    k_topscan<<<1, 512, 0, stream>>>(tot, bktstart);
    k_scatter<<<NCHK, 256, 0, stream>>>(srcp, dstp, ew, hist, bktstart, part);
    k_bucket<<<NBKT, 256, 0, stream>>>(part, bktstart, x, offs, dinv, xs_lo, xs_hi);
    k_gather<<<(N_NODES * 6 + 255) / 256, 256, 0, stream>>>(xs_lo, dinv, offs, part, xagg2, 0);
    k_gather<<<(N_NODES * 6 + 255) / 256, 256, 0, stream>>>(xs_hi, dinv, offs, part, xagg2, 6);
    k_node<<<(N_NODES + 255) / 256, 256, 0, stream>>>(xagg2, att, Wz, bz, Wh, bh,
                                                      lzW, lzb, lhW, lhb, linW, linb, out);
}

// Round 12
// 243.217 us; speedup vs baseline: 1.2716x; 1.0184x over previous
//
#include <hip/hip_runtime.h>
#include <hip/hip_fp16.h>

#define N_NODES 50000
#define N_EDGES 1600000
#define F_IN 8
#define F_OUT 12
#define PERIODS 6
#define FP 48                      // F_IN * PERIODS
#define BKT_SH 7                   // 128 nodes per bucket
#define BKT_N 128
#define NBKT ((N_NODES + BKT_N - 1) / BKT_N)   // 391
#define CHK 2048
#define NCHK ((N_EDGES + CHK - 1) / CHK)       // 782
#define SEG_CAP 4736               // mean 4096, sigma ~64, +10 sigma
#define SRC_MASK 0x1FFFFu          // src < 50000 < 2^17
#define HN 42                      // nodes per gather_hi block (42*6=252 <= 256)

// ---- pass 1: per-chunk LDS histogram over buckets ----
__global__ void __launch_bounds__(256) k_hist(const int* __restrict__ dst,
                                              unsigned int* __restrict__ hist) {
    __shared__ unsigned int h[NBKT];
    int tid = threadIdx.x, blk = blockIdx.x;
    for (int k = tid; k < NBKT; k += 256) h[k] = 0u;
    __syncthreads();
    int base = blk * CHK;
    for (int i = tid; i < CHK; i += 256) {
        int e = base + i;
        if (e < N_EDGES) atomicAdd(&h[dst[e] >> BKT_SH], 1u);
    }
    __syncthreads();
    for (int k = tid; k < NBKT; k += 256) hist[(size_t)blk * NBKT + k] = h[k];
}

// ---- pass 2a: per-bucket column exclusive scan over 782 chunks, IN PLACE ----
__global__ void __launch_bounds__(1024) k_colscan(unsigned int* __restrict__ hist,
                                                  unsigned int* __restrict__ tot) {
    __shared__ unsigned int arr[1024];
    int t = threadIdx.x, k = blockIdx.x;
    unsigned int v = (t < NCHK) ? hist[(size_t)t * NBKT + k] : 0u;
    arr[t] = v;
    __syncthreads();
    for (int off = 1; off < 1024; off <<= 1) {
        unsigned int u = (t >= off) ? arr[t - off] : 0u;
        __syncthreads();
        arr[t] += u;
        __syncthreads();
    }
    if (t < NCHK) hist[(size_t)t * NBKT + k] = arr[t] - v;  // exclusive (colpre)
    if (t == NCHK - 1) tot[k] = arr[t];                     // bucket total
}

// ---- pass 2b: exclusive scan of bucket totals ----
__global__ void __launch_bounds__(512) k_topscan(const unsigned int* __restrict__ tot,
                                                 unsigned int* __restrict__ bktstart) {
    __shared__ unsigned int arr[512];
    int t = threadIdx.x;
    unsigned int v = (t < NBKT) ? tot[t] : 0u;
    arr[t] = v;
    __syncthreads();
    for (int off = 1; off < 512; off <<= 1) {
        unsigned int u = (t >= off) ? arr[t - off] : 0u;
        __syncthreads();
        arr[t] += u;
        __syncthreads();
    }
    if (t < NBKT) bktstart[t] = arr[t] - v;  // exclusive
    if (t == NBKT - 1) bktstart[NBKT] = arr[t];
}

// ---- pass 3: scatter edges to bucket segments; rank via LDS cursor atomics ----
// entry: hi32 = ew bits, lo32 = (d&127)<<24 | src
__global__ void __launch_bounds__(256) k_scatter(const int* __restrict__ src,
                                                 const int* __restrict__ dst,
                                                 const float* __restrict__ ew,
                                                 const unsigned int* __restrict__ colpre,
                                                 const unsigned int* __restrict__ bktstart,
                                                 unsigned long long* __restrict__ part) {
    __shared__ unsigned int ldsOff[NBKT];
    int tid = threadIdx.x, blk = blockIdx.x;
    for (int k = tid; k < NBKT; k += 256)
        ldsOff[k] = bktstart[k] + colpre[(size_t)blk * NBKT + k];
    __syncthreads();
    int base = blk * CHK;
    for (int i = tid; i < CHK; i += 256) {
        int e = base + i;
        if (e >= N_EDGES) continue;
        int s = src[e], d = dst[e];
        unsigned int pos = atomicAdd(&ldsOff[d >> BKT_SH], 1u);
        unsigned int lo = ((unsigned int)(d & (BKT_N - 1)) << 24) | (unsigned int)s;
        part[pos] = ((unsigned long long)__float_as_uint(ew[e]) << 32) | lo;
    }
}

// ---- pass 4: per-bucket LDS counting sort + deg/dinv + fp16 xs halves, fused ----
__global__ void __launch_bounds__(512) k_bucket(unsigned long long* __restrict__ part,
                                                const unsigned int* __restrict__ bktstart,
                                                const float* __restrict__ x,
                                                int* __restrict__ offs,
                                                float* __restrict__ dinv_g,
                                                uint2* __restrict__ xs_lo,
                                                uint2* __restrict__ xs_hi) {
    __shared__ uint2 stage[SEG_CAP];
    __shared__ unsigned int cnt[BKT_N], cnt2[BKT_N], rowstart[BKT_N], sc[BKT_N];
    __shared__ float degf[BKT_N], dinv_l[BKT_N];
    int tid = threadIdx.x, k = blockIdx.x;
    unsigned int base = bktstart[k];
    unsigned int m = bktstart[k + 1] - base;
    if (m > SEG_CAP) m = SEG_CAP;  // 10-sigma margin; memory safety only
    if (tid < BKT_N) { cnt[tid] = 0u; cnt2[tid] = 0u; degf[tid] = 1.0f; }  // self loop
    __syncthreads();
    for (unsigned int i = tid; i < m; i += 512) {
        unsigned long long p = part[base + i];
        unsigned int lo = (unsigned int)p;
        unsigned int hi = (unsigned int)(p >> 32);
        stage[i] = make_uint2(lo, hi);
        unsigned int j = (lo >> 24) & (BKT_N - 1);
        atomicAdd(&cnt[j], 1u);
        atomicAdd(&degf[j], __uint_as_float(hi));
    }
    __syncthreads();
    if (tid < BKT_N) sc[tid] = cnt[tid];
    __syncthreads();
    for (int off = 1; off < BKT_N; off <<= 1) {
        unsigned int u = (tid >= (unsigned)off && tid < BKT_N) ? sc[tid - off] : 0u;
        __syncthreads();
        if (tid < BKT_N) sc[tid] += u;
        __syncthreads();
    }
    if (tid < BKT_N) rowstart[tid] = sc[tid] - cnt[tid];
    __syncthreads();

    int n0 = k * BKT_N;
    int nn = N_NODES - n0; if (nn > BKT_N) nn = BKT_N;

    if (tid < BKT_N) {
        float dv = rsqrtf(degf[tid]);
        dinv_l[tid] = dv;
        if (tid < nn) {
            dinv_g[n0 + tid] = dv;
            offs[n0 + tid] = (int)(base + rowstart[tid]);
        }
    }
    if (k == NBKT - 1 && tid == 0) offs[N_NODES] = N_EDGES;

    // sorted in-place write (reads from LDS stage — no hazard)
    for (unsigned int i = tid; i < m; i += 512) {
        uint2 v = stage[i];
        unsigned int j = (v.x >> 24) & (BKT_N - 1);
        unsigned int r = atomicAdd(&cnt2[j], 1u);
        part[base + rowstart[j] + r] = ((unsigned long long)v.y << 32) | v.x;
    }
    __syncthreads();

    // xs_lo/xs_hi[n*6+c] = fp16(dinv[n] * x[n, chunk]) — chunk c covers feats 4c..4c+3
    for (int idx = tid; idx < nn * 12; idx += 512) {
        int j = idx / 12, c = idx % 12;
        int n = n0 + j;
        float di = dinv_l[j];
        const float4* xr = (const float4*)(x + (size_t)n * FP + c * 4);
        float4 a = xr[0];
        __half2 h0 = __floats2half2_rn(di * a.x, di * a.y);
        __half2 h1 = __floats2half2_rn(di * a.z, di * a.w);
        uint2 o;
        o.x = *(unsigned int*)&h0; o.y = *(unsigned int*)&h1;
        if (c < 6) xs_lo[(size_t)n * 6 + c] = o;
        else       xs_hi[(size_t)n * 6 + (c - 6)] = o;
    }
}

// 4-wide unrolled edge accumulation: 4 independent xs loads in flight
__device__ __forceinline__ void edge_acc(const uint2* __restrict__ xs_h,
                                         const unsigned long long* __restrict__ part,
                                         int b, int e, int c,
                                         float& a0, float& a1, float& a2, float& a3) {
    int kk = b;
    for (; kk + 4 <= e; kk += 4) {
        unsigned long long p0 = part[kk], p1 = part[kk + 1];
        unsigned long long p2 = part[kk + 2], p3 = part[kk + 3];
        uint2 v0 = xs_h[(size_t)((unsigned int)p0 & SRC_MASK) * 6 + c];
        uint2 v1 = xs_h[(size_t)((unsigned int)p1 & SRC_MASK) * 6 + c];
        uint2 v2 = xs_h[(size_t)((unsigned int)p2 & SRC_MASK) * 6 + c];
        uint2 v3 = xs_h[(size_t)((unsigned int)p3 & SRC_MASK) * 6 + c];
        float w0 = __uint_as_float((unsigned int)(p0 >> 32));
        float w1 = __uint_as_float((unsigned int)(p1 >> 32));
        float w2 = __uint_as_float((unsigned int)(p2 >> 32));
        float w3 = __uint_as_float((unsigned int)(p3 >> 32));
        float2 e0, e1;
        e0 = __half22float2(*(__half2*)&v0.x); e1 = __half22float2(*(__half2*)&v0.y);
        a0 += w0 * e0.x; a1 += w0 * e0.y; a2 += w0 * e1.x; a3 += w0 * e1.y;
        e0 = __half22float2(*(__half2*)&v1.x); e1 = __half22float2(*(__half2*)&v1.y);
        a0 += w1 * e0.x; a1 += w1 * e0.y; a2 += w1 * e1.x; a3 += w1 * e1.y;
        e0 = __half22float2(*(__half2*)&v2.x); e1 = __half22float2(*(__half2*)&v2.y);
        a0 += w2 * e0.x; a1 += w2 * e0.y; a2 += w2 * e1.x; a3 += w2 * e1.y;
        e0 = __half22float2(*(__half2*)&v3.x); e1 = __half22float2(*(__half2*)&v3.y);
        a0 += w3 * e0.x; a1 += w3 * e0.y; a2 += w3 * e1.x; a3 += w3 * e1.y;
    }
    for (; kk < e; kk++) {
        unsigned long long p = part[kk];
        float w = __uint_as_float((unsigned int)(p >> 32));
        uint2 v = xs_h[(size_t)((unsigned int)p & SRC_MASK) * 6 + c];
        float2 e0 = __half22float2(*(__half2*)&v.x);
        float2 e1 = __half22float2(*(__half2*)&v.y);
        a0 += w * e0.x; a1 += w * e0.y; a2 += w * e1.x; a3 += w * e1.y;
    }
}

// ---- pass 5a: low-half gather -> fp16 xagg_lo (layout [n*6+c]) ----
__global__ void __launch_bounds__(256) k_gather_lo(const uint2* __restrict__ xs_lo,
                                                   const float* __restrict__ dinv,
                                                   const int* __restrict__ offs,
                                                   const unsigned long long* __restrict__ part,
                                                   uint2* __restrict__ xagg_lo) {
    int t = blockIdx.x * 256 + threadIdx.x;
    if (t >= N_NODES * 6) return;
    int n = t / 6, c = t % 6;
    uint2 self = xs_lo[(size_t)n * 6 + c];
    float2 f0 = __half22float2(*(__half2*)&self.x);
    float2 f1 = __half22float2(*(__half2*)&self.y);
    float a0 = f0.x, a1 = f0.y, a2 = f1.x, a3 = f1.y;
    edge_acc(xs_lo, part, offs[n], offs[n + 1], c, a0, a1, a2, a3);
    float di = dinv[n];
    __half2 o0 = __floats2half2_rn(di * a0, di * a1);
    __half2 o1 = __floats2half2_rn(di * a2, di * a3);
    uint2 o;
    o.x = *(unsigned int*)&o0; o.y = *(unsigned int*)&o1;
    xagg_lo[(size_t)n * 6 + c] = o;
}

// ---- pass 5b: high-half gather + fused epilogue (gates/att/relu/linear) ----
// H0 == 0 => R gate dead; Z/Ht use only first F_OUT cols of lzW/lhW.
__global__ void __launch_bounds__(256) k_gather_hi(const uint2* __restrict__ xs_hi,
                                                   const float* __restrict__ dinv,
                                                   const int* __restrict__ offs,
                                                   const unsigned long long* __restrict__ part,
                                                   const uint2* __restrict__ xagg_lo,
                                                   const float* __restrict__ att,
                                                   const float* __restrict__ Wz, const float* __restrict__ bz,
                                                   const float* __restrict__ Wh, const float* __restrict__ bh,
                                                   const float* __restrict__ lzW, const float* __restrict__ lzb,
                                                   const float* __restrict__ lhW, const float* __restrict__ lhb,
                                                   const float* __restrict__ linW, const float* __restrict__ linb,
                                                   float* __restrict__ out) {
    __shared__ float xrow[HN][25];  // hi half (feats 24..47), padded stride
    int tid = threadIdx.x;
    int nl = tid / 6, c = tid % 6;
    int n = blockIdx.x * HN + nl;
    if (tid < HN * 6 && n < N_NODES) {
        uint2 self = xs_hi[(size_t)n * 6 + c];
        float2 f0 = __half22float2(*(__half2*)&self.x);
        float2 f1 = __half22float2(*(__half2*)&self.y);
        float a0 = f0.x, a1 = f0.y, a2 = f1.x, a3 = f1.y;
        edge_acc(xs_hi, part, offs[n], offs[n + 1], c, a0, a1, a2, a3);
        float di = dinv[n];
        xrow[nl][c * 4] = di * a0; xrow[nl][c * 4 + 1] = di * a1;
        xrow[nl][c * 4 + 2] = di * a2; xrow[nl][c * 4 + 3] = di * a3;
    }
    __syncthreads();
    if (tid >= HN) return;
    int n2 = blockIdx.x * HN + tid;
    if (n2 >= N_NODES) return;

    // softmax(att)
    float a[PERIODS];
    float mm = -1e30f;
    #pragma unroll
    for (int p = 0; p < PERIODS; p++) { a[p] = att[p]; mm = fmaxf(mm, a[p]); }
    float se = 0.f;
    #pragma unroll
    for (int p = 0; p < PERIODS; p++) { a[p] = __expf(a[p] - mm); se += a[p]; }
    float inv = 1.f / se;
    #pragma unroll
    for (int p = 0; p < PERIODS; p++) a[p] *= inv;

    float row[FP];
    {
        const uint2* xr = xagg_lo + (size_t)n2 * 6;
        #pragma unroll
        for (int i = 0; i < 6; i++) {
            uint2 v = xr[i];
            float2 f0 = __half22float2(*(__half2*)&v.x);
            float2 f1 = __half22float2(*(__half2*)&v.y);
            row[4 * i] = f0.x; row[4 * i + 1] = f0.y;
            row[4 * i + 2] = f1.x; row[4 * i + 3] = f1.y;
        }
        #pragma unroll
        for (int q = 0; q < 24; q++) row[24 + q] = xrow[tid][q];
    }

    float H[F_OUT];
    #pragma unroll
    for (int j = 0; j < F_OUT; j++) H[j] = 0.f;

    for (int p = 0; p < PERIODS; p++) {
        float gz[F_OUT], gh[F_OUT];
        #pragma unroll
        for (int j = 0; j < F_OUT; j++) { gz[j] = bz[j]; gh[j] = bh[j]; }
        #pragma unroll
        for (int f = 0; f < F_IN; f++) {
            float xv = row[f * PERIODS + p];
            #pragma unroll
            for (int j = 0; j < F_OUT; j++) {
                gz[j] += xv * Wz[f * F_OUT + j];
                gh[j] += xv * Wh[f * F_OUT + j];
            }
        }
        #pragma unroll
        for (int j = 0; j < F_OUT; j++) {
            float z = lzb[j], t2 = lhb[j];
            #pragma unroll
            for (int kk = 0; kk < F_OUT; kk++) {
                z  += gz[kk] * lzW[j * (2 * F_OUT) + kk];
                t2 += gh[kk] * lhW[j * (2 * F_OUT) + kk];
            }
            float Z = 1.f / (1.f + __expf(-z));
            H[j] += a[p] * (1.f - Z) * tanhf(t2);
        }
    }

    float* op = out + (size_t)n2 * PERIODS;
    #pragma unroll
    for (int q = 0; q < PERIODS; q++) {
        float acc = linb[q];
        #pragma unroll
        for (int j = 0; j < F_OUT; j++)
            acc += fmaxf(H[j], 0.f) * linW[q * F_OUT + j];
        op[q] = acc;
    }
}

extern "C" void kernel_launch(void* const* d_in, const int* in_sizes, int n_in,
                              void* d_out, int out_size, void* d_ws, size_t ws_size,
                              hipStream_t stream) {
    const float* x    = (const float*)d_in[0];
    const int*   ei   = (const int*)d_in[1];
    const float* ew   = (const float*)d_in[2];
    const float* att  = (const float*)d_in[3];
    const float* Wz   = (const float*)d_in[4];
    const float* bz   = (const float*)d_in[5];
    // d_in[6]=Wr, d_in[7]=br : dead (H0 == 0)
    const float* Wh   = (const float*)d_in[8];
    const float* bh   = (const float*)d_in[9];
    const float* lzW  = (const float*)d_in[10];
    const float* lzb  = (const float*)d_in[11];
    // d_in[12]=lrW, d_in[13]=lrb : dead
    const float* lhW  = (const float*)d_in[14];
    const float* lhb  = (const float*)d_in[15];
    const float* linW = (const float*)d_in[16];
    const float* linb = (const float*)d_in[17];
    float* out = (float*)d_out;

    // ws layout (~21 MB)
    unsigned long long* part = (unsigned long long*)d_ws;            // E * 8B (sorted in place)
    uint2* xs_lo = (uint2*)(part + N_EDGES);                         // N*6 uint2 = 2.4 MB
    uint2* xs_hi = xs_lo + (size_t)N_NODES * 6;                      // N*6 uint2 = 2.4 MB
    uint2* xagg_lo = xs_hi + (size_t)N_NODES * 6;                    // N*6 uint2 = 2.4 MB
    unsigned int* hist = (unsigned int*)(xagg_lo + (size_t)N_NODES * 6); // NCHK*NBKT u32
    float* dinv = (float*)(hist + (size_t)NCHK * NBKT);              // N floats
    int*   offs = (int*)(dinv + N_NODES);                            // N+1 ints
    unsigned int* bktstart = (unsigned int*)(offs + N_NODES + 1);    // NBKT+1 u32
    unsigned int* tot = bktstart + NBKT + 1;                         // NBKT u32

    const int* srcp = ei;
    const int* dstp = ei + N_EDGES;

    k_hist<<<NCHK, 256, 0, stream>>>(dstp, hist);
    k_colscan<<<NBKT, 1024, 0, stream>>>(hist, tot);
    k_topscan<<<1, 512, 0, stream>>>(tot, bktstart);
    k_scatter<<<NCHK, 256, 0, stream>>>(srcp, dstp, ew, hist, bktstart, part);
    k_bucket<<<NBKT, 512, 0, stream>>>(part, bktstart, x, offs, dinv, xs_lo, xs_hi);
    k_gather_lo<<<(N_NODES * 6 + 255) / 256, 256, 0, stream>>>(xs_lo, dinv, offs, part, xagg_lo);
    k_gather_hi<<<(N_NODES + HN - 1) / HN, 256, 0, stream>>>(
        xs_hi, dinv, offs, part, xagg_lo, att, Wz, bz, Wh, bh,
        lzW, lzb, lhW, lhb, linW, linb, out);
}

// Round 13
// 223.340 us; speedup vs baseline: 1.3847x; 1.0890x over previous
//
#include <hip/hip_runtime.h>
#include <hip/hip_fp16.h>

#define N_NODES 50000
#define N_EDGES 1600000
#define F_IN 8
#define F_OUT 12
#define PERIODS 6
#define FP 48                      // F_IN * PERIODS
#define BKT_SH 7                   // 128 nodes per bucket
#define BKT_N 128
#define NBKT ((N_NODES + BKT_N - 1) / BKT_N)   // 391
#define CHK 2048
#define NCHK ((N_EDGES + CHK - 1) / CHK)       // 782
#define SEG_CAP 4736               // mean 4096, sigma ~64, +10 sigma
#define SRC_MASK 0x1FFFFu          // src < 50000 < 2^17

// ---- pass 1: per-chunk LDS histogram over buckets ----
__global__ void __launch_bounds__(256) k_hist(const int* __restrict__ dst,
                                              unsigned int* __restrict__ hist) {
    __shared__ unsigned int h[NBKT];
    int tid = threadIdx.x, blk = blockIdx.x;
    for (int k = tid; k < NBKT; k += 256) h[k] = 0u;
    __syncthreads();
    int base = blk * CHK;
    for (int i = tid; i < CHK; i += 256) {
        int e = base + i;
        if (e < N_EDGES) atomicAdd(&h[dst[e] >> BKT_SH], 1u);
    }
    __syncthreads();
    for (int k = tid; k < NBKT; k += 256) hist[(size_t)blk * NBKT + k] = h[k];
}

// ---- pass 2a: per-bucket column exclusive scan over 782 chunks, IN PLACE ----
__global__ void __launch_bounds__(1024) k_colscan(unsigned int* __restrict__ hist,
                                                  unsigned int* __restrict__ tot) {
    __shared__ unsigned int arr[1024];
    int t = threadIdx.x, k = blockIdx.x;
    unsigned int v = (t < NCHK) ? hist[(size_t)t * NBKT + k] : 0u;
    arr[t] = v;
    __syncthreads();
    for (int off = 1; off < 1024; off <<= 1) {
        unsigned int u = (t >= off) ? arr[t - off] : 0u;
        __syncthreads();
        arr[t] += u;
        __syncthreads();
    }
    if (t < NCHK) hist[(size_t)t * NBKT + k] = arr[t] - v;  // exclusive (colpre)
    if (t == NCHK - 1) tot[k] = arr[t];                     // bucket total
}

// ---- pass 2b: exclusive scan of bucket totals ----
__global__ void __launch_bounds__(512) k_topscan(const unsigned int* __restrict__ tot,
                                                 unsigned int* __restrict__ bktstart) {
    __shared__ unsigned int arr[512];
    int t = threadIdx.x;
    unsigned int v = (t < NBKT) ? tot[t] : 0u;
    arr[t] = v;
    __syncthreads();
    for (int off = 1; off < 512; off <<= 1) {
        unsigned int u = (t >= off) ? arr[t - off] : 0u;
        __syncthreads();
        arr[t] += u;
        __syncthreads();
    }
    if (t < NBKT) bktstart[t] = arr[t] - v;  // exclusive
    if (t == NBKT - 1) bktstart[NBKT] = arr[t];
}

// ---- pass 3: scatter edges to bucket segments; rank via LDS cursor atomics ----
// entry: hi32 = ew bits, lo32 = (d&127)<<24 | src
__global__ void __launch_bounds__(256) k_scatter(const int* __restrict__ src,
                                                 const int* __restrict__ dst,
                                                 const float* __restrict__ ew,
                                                 const unsigned int* __restrict__ colpre,
                                                 const unsigned int* __restrict__ bktstart,
                                                 unsigned long long* __restrict__ part) {
    __shared__ unsigned int ldsOff[NBKT];
    int tid = threadIdx.x, blk = blockIdx.x;
    for (int k = tid; k < NBKT; k += 256)
        ldsOff[k] = bktstart[k] + colpre[(size_t)blk * NBKT + k];
    __syncthreads();
    int base = blk * CHK;
    for (int i = tid; i < CHK; i += 256) {
        int e = base + i;
        if (e >= N_EDGES) continue;
        int s = src[e], d = dst[e];
        unsigned int pos = atomicAdd(&ldsOff[d >> BKT_SH], 1u);
        unsigned int lo = ((unsigned int)(d & (BKT_N - 1)) << 24) | (unsigned int)s;
        part[pos] = ((unsigned long long)__float_as_uint(ew[e]) << 32) | lo;
    }
}

// ---- pass 4: per-bucket LDS counting sort + deg/dinv + fp16 xs, fused ----
__global__ void __launch_bounds__(512) k_bucket(unsigned long long* __restrict__ part,
                                                const unsigned int* __restrict__ bktstart,
                                                const float* __restrict__ x,
                                                int* __restrict__ offs,
                                                float* __restrict__ dinv_g,
                                                uint2* __restrict__ xs) {
    __shared__ uint2 stage[SEG_CAP];
    __shared__ unsigned int cnt[BKT_N], cnt2[BKT_N], rowstart[BKT_N], sc[BKT_N];
    __shared__ float degf[BKT_N], dinv_l[BKT_N];
    int tid = threadIdx.x, k = blockIdx.x;
    unsigned int base = bktstart[k];
    unsigned int m = bktstart[k + 1] - base;
    if (m > SEG_CAP) m = SEG_CAP;  // 10-sigma margin; memory safety only
    if (tid < BKT_N) { cnt[tid] = 0u; cnt2[tid] = 0u; degf[tid] = 1.0f; }  // self loop
    __syncthreads();
    for (unsigned int i = tid; i < m; i += 512) {
        unsigned long long p = part[base + i];
        unsigned int lo = (unsigned int)p;
        unsigned int hi = (unsigned int)(p >> 32);
        stage[i] = make_uint2(lo, hi);
        unsigned int j = (lo >> 24) & (BKT_N - 1);
        atomicAdd(&cnt[j], 1u);
        atomicAdd(&degf[j], __uint_as_float(hi));
    }
    __syncthreads();
    if (tid < BKT_N) sc[tid] = cnt[tid];
    __syncthreads();
    for (int off = 1; off < BKT_N; off <<= 1) {
        unsigned int u = (tid >= (unsigned)off && tid < BKT_N) ? sc[tid - off] : 0u;
        __syncthreads();
        if (tid < BKT_N) sc[tid] += u;
        __syncthreads();
    }
    if (tid < BKT_N) rowstart[tid] = sc[tid] - cnt[tid];
    __syncthreads();

    int n0 = k * BKT_N;
    int nn = N_NODES - n0; if (nn > BKT_N) nn = BKT_N;

    if (tid < BKT_N) {
        float dv = rsqrtf(degf[tid]);
        dinv_l[tid] = dv;
        if (tid < nn) {
            dinv_g[n0 + tid] = dv;
            offs[n0 + tid] = (int)(base + rowstart[tid]);
        }
    }
    if (k == NBKT - 1 && tid == 0) offs[N_NODES] = N_EDGES;

    // sorted in-place write (reads from LDS stage — no hazard)
    for (unsigned int i = tid; i < m; i += 512) {
        uint2 v = stage[i];
        unsigned int j = (v.x >> 24) & (BKT_N - 1);
        unsigned int r = atomicAdd(&cnt2[j], 1u);
        part[base + rowstart[j] + r] = ((unsigned long long)v.y << 32) | v.x;
    }
    __syncthreads();

    // xs[n*12+c] = fp16(dinv[n] * x[n, 4c..4c+3])  (coalesced, uint2 per chunk)
    for (int idx = tid; idx < nn * 12; idx += 512) {
        int j = idx / 12, c = idx % 12;
        int n = n0 + j;
        float di = dinv_l[j];
        const float4* xr = (const float4*)(x + (size_t)n * FP + c * 4);
        float4 a = xr[0];
        __half2 h0 = __floats2half2_rn(di * a.x, di * a.y);
        __half2 h1 = __floats2half2_rn(di * a.z, di * a.w);
        uint2 o;
        o.x = *(unsigned int*)&h0; o.y = *(unsigned int*)&h1;
        xs[(size_t)n * 12 + c] = o;
    }
}

// ---- pass 5: 12-lane/node gather, 4-wide MLP unroll, no barriers ----
// xagg[n] = fp16( dinv[n] * (xs[n] + sum ew_e * xs[src_e]) )
__global__ void __launch_bounds__(256) k_gather(const uint2* __restrict__ xs,
                                                const float* __restrict__ dinv,
                                                const int* __restrict__ offs,
                                                const unsigned long long* __restrict__ part,
                                                uint2* __restrict__ xagg2) {
    int t = blockIdx.x * 256 + threadIdx.x;
    if (t >= N_NODES * 12) return;
    int n = t / 12, c = t % 12;
    uint2 self = xs[(size_t)n * 12 + c];
    float2 f0 = __half22float2(*(__half2*)&self.x);
    float2 f1 = __half22float2(*(__half2*)&self.y);
    float a0 = f0.x, a1 = f0.y, a2 = f1.x, a3 = f1.y;
    int b = offs[n], e = offs[n + 1];
    int kk = b;
    for (; kk + 4 <= e; kk += 4) {
        unsigned long long p0 = part[kk], p1 = part[kk + 1];
        unsigned long long p2 = part[kk + 2], p3 = part[kk + 3];
        uint2 v0 = xs[(size_t)((unsigned int)p0 & SRC_MASK) * 12 + c];
        uint2 v1 = xs[(size_t)((unsigned int)p1 & SRC_MASK) * 12 + c];
        uint2 v2 = xs[(size_t)((unsigned int)p2 & SRC_MASK) * 12 + c];
        uint2 v3 = xs[(size_t)((unsigned int)p3 & SRC_MASK) * 12 + c];
        float w0 = __uint_as_float((unsigned int)(p0 >> 32));
        float w1 = __uint_as_float((unsigned int)(p1 >> 32));
        float w2 = __uint_as_float((unsigned int)(p2 >> 32));
        float w3 = __uint_as_float((unsigned int)(p3 >> 32));
        float2 e0, e1;
        e0 = __half22float2(*(__half2*)&v0.x); e1 = __half22float2(*(__half2*)&v0.y);
        a0 += w0 * e0.x; a1 += w0 * e0.y; a2 += w0 * e1.x; a3 += w0 * e1.y;
        e0 = __half22float2(*(__half2*)&v1.x); e1 = __half22float2(*(__half2*)&v1.y);
        a0 += w1 * e0.x; a1 += w1 * e0.y; a2 += w1 * e1.x; a3 += w1 * e1.y;
        e0 = __half22float2(*(__half2*)&v2.x); e1 = __half22float2(*(__half2*)&v2.y);
        a0 += w2 * e0.x; a1 += w2 * e0.y; a2 += w2 * e1.x; a3 += w2 * e1.y;
        e0 = __half22float2(*(__half2*)&v3.x); e1 = __half22float2(*(__half2*)&v3.y);
        a0 += w3 * e0.x; a1 += w3 * e0.y; a2 += w3 * e1.x; a3 += w3 * e1.y;
    }
    for (; kk < e; kk++) {
        unsigned long long p = part[kk];
        float w = __uint_as_float((unsigned int)(p >> 32));
        uint2 v = xs[(size_t)((unsigned int)p & SRC_MASK) * 12 + c];
        float2 e0 = __half22float2(*(__half2*)&v.x);
        float2 e1 = __half22float2(*(__half2*)&v.y);
        a0 += w * e0.x; a1 += w * e0.y; a2 += w * e1.x; a3 += w * e1.y;
    }
    float di = dinv[n];
    __half2 o0 = __floats2half2_rn(di * a0, di * a1);
    __half2 o1 = __floats2half2_rn(di * a2, di * a3);
    uint2 o;
    o.x = *(unsigned int*)&o0; o.y = *(unsigned int*)&o1;
    xagg2[(size_t)n * 12 + c] = o;
}

// ---- pass 6: per-node fused epilogue (gates + attention + relu + linear) ----
// H0 == 0 => R gate dead; Z/Ht use only first F_OUT cols of lzW/lhW.
__global__ void k_node(const uint2* __restrict__ xagg2, const float* __restrict__ att,
                       const float* __restrict__ Wz, const float* __restrict__ bz,
                       const float* __restrict__ Wh, const float* __restrict__ bh,
                       const float* __restrict__ lzW, const float* __restrict__ lzb,
                       const float* __restrict__ lhW, const float* __restrict__ lhb,
                       const float* __restrict__ linW, const float* __restrict__ linb,
                       float* __restrict__ out) {
    int n = blockIdx.x * blockDim.x + threadIdx.x;
    if (n >= N_NODES) return;

    float a[PERIODS];
    float m = -1e30f;
    #pragma unroll
    for (int p = 0; p < PERIODS; p++) { a[p] = att[p]; m = fmaxf(m, a[p]); }
    float se = 0.f;
    #pragma unroll
    for (int p = 0; p < PERIODS; p++) { a[p] = __expf(a[p] - m); se += a[p]; }
    float inv = 1.f / se;
    #pragma unroll
    for (int p = 0; p < PERIODS; p++) a[p] *= inv;

    float row[FP];
    const uint2* xr = xagg2 + (size_t)n * 12;
    #pragma unroll
    for (int i = 0; i < 12; i++) {
        uint2 v = xr[i];
        float2 f0 = __half22float2(*(__half2*)&v.x);
        float2 f1 = __half22float2(*(__half2*)&v.y);
        row[4 * i] = f0.x; row[4 * i + 1] = f0.y;
        row[4 * i + 2] = f1.x; row[4 * i + 3] = f1.y;
    }

    float H[F_OUT];
    #pragma unroll
    for (int j = 0; j < F_OUT; j++) H[j] = 0.f;

    for (int p = 0; p < PERIODS; p++) {
        float gz[F_OUT], gh[F_OUT];
        #pragma unroll
        for (int j = 0; j < F_OUT; j++) { gz[j] = bz[j]; gh[j] = bh[j]; }
        #pragma unroll
        for (int f = 0; f < F_IN; f++) {
            float xv = row[f * PERIODS + p];
            #pragma unroll
            for (int j = 0; j < F_OUT; j++) {
                gz[j] += xv * Wz[f * F_OUT + j];
                gh[j] += xv * Wh[f * F_OUT + j];
            }
        }
        #pragma unroll
        for (int j = 0; j < F_OUT; j++) {
            float z = lzb[j], t2 = lhb[j];
            #pragma unroll
            for (int kk = 0; kk < F_OUT; kk++) {
                z  += gz[kk] * lzW[j * (2 * F_OUT) + kk];
                t2 += gh[kk] * lhW[j * (2 * F_OUT) + kk];
            }
            float Z = 1.f / (1.f + __expf(-z));
            H[j] += a[p] * (1.f - Z) * tanhf(t2);
        }
    }

    float* op = out + (size_t)n * PERIODS;
    #pragma unroll
    for (int q = 0; q < PERIODS; q++) {
        float acc = linb[q];
        #pragma unroll
        for (int j = 0; j < F_OUT; j++)
            acc += fmaxf(H[j], 0.f) * linW[q * F_OUT + j];
        op[q] = acc;
    }
}

extern "C" void kernel_launch(void* const* d_in, const int* in_sizes, int n_in,
                              void* d_out, int out_size, void* d_ws, size_t ws_size,
                              hipStream_t stream) {
    const float* x    = (const float*)d_in[0];
    const int*   ei   = (const int*)d_in[1];
    const float* ew   = (const float*)d_in[2];
    const float* att  = (const float*)d_in[3];
    const float* Wz   = (const float*)d_in[4];
    const float* bz   = (const float*)d_in[5];
    // d_in[6]=Wr, d_in[7]=br : dead (H0 == 0)
    const float* Wh   = (const float*)d_in[8];
    const float* bh   = (const float*)d_in[9];
    const float* lzW  = (const float*)d_in[10];
    const float* lzb  = (const float*)d_in[11];
    // d_in[12]=lrW, d_in[13]=lrb : dead
    const float* lhW  = (const float*)d_in[14];
    const float* lhb  = (const float*)d_in[15];
    const float* linW = (const float*)d_in[16];
    const float* linb = (const float*)d_in[17];
    float* out = (float*)d_out;

    // ws layout (~25 MB)
    unsigned long long* part = (unsigned long long*)d_ws;            // E * 8B (sorted in place)
    uint2* xs = (uint2*)(part + N_EDGES);                            // N*12 uint2 = 4.8 MB
    uint2* xagg2 = xs + (size_t)N_NODES * 12;                        // N*12 uint2 = 4.8 MB
    unsigned int* hist = (unsigned int*)(xagg2 + (size_t)N_NODES * 12); // NCHK*NBKT u32
    float* dinv = (float*)(hist + (size_t)NCHK * NBKT);              // N floats
    int*   offs = (int*)(dinv + N_NODES);                            // N+1 ints
    unsigned int* bktstart = (unsigned int*)(offs + N_NODES + 1);    // NBKT+1 u32
    unsigned int* tot = bktstart + NBKT + 1;                         // NBKT u32

    const int* srcp = ei;
    const int* dstp = ei + N_EDGES;

    k_hist<<<NCHK, 256, 0, stream>>>(dstp, hist);
    k_colscan<<<NBKT, 1024, 0, stream>>>(hist, tot);
    k_topscan<<<1, 512, 0, stream>>>(tot, bktstart);
    k_scatter<<<NCHK, 256, 0, stream>>>(srcp, dstp, ew, hist, bktstart, part);
    k_bucket<<<NBKT, 512, 0, stream>>>(part, bktstart, x, offs, dinv, xs);
    k_gather<<<(N_NODES * 12 + 255) / 256, 256, 0, stream>>>(xs, dinv, offs, part, xagg2);
    k_node<<<(N_NODES + 255) / 256, 256, 0, stream>>>(xagg2, att, Wz, bz, Wh, bh,
                                                      lzW, lzb, lhW, lhb, linW, linb, out);
}

// Round 14
// 220.431 us; speedup vs baseline: 1.4030x; 1.0132x over previous
//
#include <hip/hip_runtime.h>
#include <hip/hip_fp16.h>

#define N_NODES 50000
#define N_EDGES 1600000
#define F_IN 8
#define F_OUT 12
#define PERIODS 6
#define FP 48                      // F_IN * PERIODS
#define BKT_SH 7                   // 128 nodes per bucket
#define BKT_N 128
#define NBKT ((N_NODES + BKT_N - 1) / BKT_N)   // 391
#define CHK 2048
#define NCHK ((N_EDGES + CHK - 1) / CHK)       // 782
#define SEG_CAP 4736               // mean 4092, sigma ~64, +10 sigma
#define SRC_MASK 0x1FFFFu          // src < 50000 < 2^17

// ---- pass 1: per-chunk LDS histogram over buckets ----
__global__ void __launch_bounds__(256) k_hist(const int* __restrict__ dst,
                                              unsigned int* __restrict__ hist) {
    __shared__ unsigned int h[NBKT];
    int tid = threadIdx.x, blk = blockIdx.x;
    for (int k = tid; k < NBKT; k += 256) h[k] = 0u;
    __syncthreads();
    int base = blk * CHK;
    for (int i = tid; i < CHK; i += 256) {
        int e = base + i;
        if (e < N_EDGES) atomicAdd(&h[dst[e] >> BKT_SH], 1u);
    }
    __syncthreads();
    for (int k = tid; k < NBKT; k += 256) hist[(size_t)blk * NBKT + k] = h[k];
}

// ---- pass 2: per-bucket column exclusive scan over 782 chunks, IN PLACE; emits tot ----
__global__ void __launch_bounds__(1024) k_colscan(unsigned int* __restrict__ hist,
                                                  unsigned int* __restrict__ tot) {
    __shared__ unsigned int arr[1024];
    int t = threadIdx.x, k = blockIdx.x;
    unsigned int v = (t < NCHK) ? hist[(size_t)t * NBKT + k] : 0u;
    arr[t] = v;
    __syncthreads();
    for (int off = 1; off < 1024; off <<= 1) {
        unsigned int u = (t >= off) ? arr[t - off] : 0u;
        __syncthreads();
        arr[t] += u;
        __syncthreads();
    }
    if (t < NCHK) hist[(size_t)t * NBKT + k] = arr[t] - v;  // exclusive (colpre)
    if (t == NCHK - 1) tot[k] = arr[t];                     // bucket total
}

// ---- pass 3: scatter edges to bucket segments; bktstart recomputed per block ----
// entry: hi32 = ew bits, lo32 = (d&127)<<24 | src
__global__ void __launch_bounds__(512) k_scatter(const int* __restrict__ src,
                                                 const int* __restrict__ dst,
                                                 const float* __restrict__ ew,
                                                 const unsigned int* __restrict__ colpre,
                                                 const unsigned int* __restrict__ tot,
                                                 unsigned long long* __restrict__ part) {
    __shared__ unsigned int arr[512];
    __shared__ unsigned int ldsOff[NBKT];
    int tid = threadIdx.x, blk = blockIdx.x;
    // LDS scan of the 391 bucket totals -> bucket starts
    unsigned int v = (tid < NBKT) ? tot[tid] : 0u;
    arr[tid] = v;
    __syncthreads();
    for (int off = 1; off < 512; off <<= 1) {
        unsigned int u = (tid >= off) ? arr[tid - off] : 0u;
        __syncthreads();
        arr[tid] += u;
        __syncthreads();
    }
    if (tid < NBKT)
        ldsOff[tid] = (arr[tid] - v) + colpre[(size_t)blk * NBKT + tid];
    __syncthreads();
    int base = blk * CHK;
    for (int i = tid; i < CHK; i += 512) {
        int e = base + i;
        if (e >= N_EDGES) continue;
        int s = src[e], d = dst[e];
        unsigned int pos = atomicAdd(&ldsOff[d >> BKT_SH], 1u);
        unsigned int lo = ((unsigned int)(d & (BKT_N - 1)) << 24) | (unsigned int)s;
        part[pos] = ((unsigned long long)__float_as_uint(ew[e]) << 32) | lo;
    }
}

// ---- pass 4: per-bucket LDS counting sort + deg/dinv + fp16 xs, fused ----
__global__ void __launch_bounds__(512) k_bucket(unsigned long long* __restrict__ part,
                                                const unsigned int* __restrict__ tot,
                                                const float* __restrict__ x,
                                                int* __restrict__ offs,
                                                float* __restrict__ dinv_g,
                                                uint2* __restrict__ xs) {
    __shared__ uint2 stage[SEG_CAP];
    __shared__ unsigned int arr[512];
    __shared__ unsigned int cnt[BKT_N], cnt2[BKT_N], rowstart[BKT_N], sc[BKT_N];
    __shared__ float degf[BKT_N], dinv_l[BKT_N];
    int tid = threadIdx.x, k = blockIdx.x;
    // LDS scan of tot -> this bucket's base
    unsigned int v = (tid < NBKT) ? tot[tid] : 0u;
    arr[tid] = v;
    __syncthreads();
    for (int off = 1; off < 512; off <<= 1) {
        unsigned int u = (tid >= off) ? arr[tid - off] : 0u;
        __syncthreads();
        arr[tid] += u;
        __syncthreads();
    }
    unsigned int base = (k > 0) ? arr[k - 1] : 0u;  // exclusive prefix at k
    unsigned int m = tot[k];
    if (m > SEG_CAP) m = SEG_CAP;  // 10-sigma margin; memory safety only
    if (tid < BKT_N) { cnt[tid] = 0u; cnt2[tid] = 0u; degf[tid] = 1.0f; }  // self loop
    __syncthreads();
    for (unsigned int i = tid; i < m; i += 512) {
        unsigned long long p = part[base + i];
        unsigned int lo = (unsigned int)p;
        unsigned int hi = (unsigned int)(p >> 32);
        stage[i] = make_uint2(lo, hi);
        unsigned int j = (lo >> 24) & (BKT_N - 1);
        atomicAdd(&cnt[j], 1u);
        atomicAdd(&degf[j], __uint_as_float(hi));
    }
    __syncthreads();
    if (tid < BKT_N) sc[tid] = cnt[tid];
    __syncthreads();
    for (int off = 1; off < BKT_N; off <<= 1) {
        unsigned int u = (tid >= (unsigned)off && tid < BKT_N) ? sc[tid - off] : 0u;
        __syncthreads();
        if (tid < BKT_N) sc[tid] += u;
        __syncthreads();
    }
    if (tid < BKT_N) rowstart[tid] = sc[tid] - cnt[tid];
    __syncthreads();

    int n0 = k * BKT_N;
    int nn = N_NODES - n0; if (nn > BKT_N) nn = BKT_N;

    if (tid < BKT_N) {
        float dv = rsqrtf(degf[tid]);
        dinv_l[tid] = dv;
        if (tid < nn) {
            dinv_g[n0 + tid] = dv;
            offs[n0 + tid] = (int)(base + rowstart[tid]);
        }
    }
    if (k == NBKT - 1 && tid == 0) offs[N_NODES] = N_EDGES;

    // sorted in-place write (reads from LDS stage — no hazard)
    for (unsigned int i = tid; i < m; i += 512) {
        uint2 vv = stage[i];
        unsigned int j = (vv.x >> 24) & (BKT_N - 1);
        unsigned int r = atomicAdd(&cnt2[j], 1u);
        part[base + rowstart[j] + r] = ((unsigned long long)vv.y << 32) | vv.x;
    }
    __syncthreads();

    // xs[n*12+c] = fp16(dinv[n] * x[n, 4c..4c+3])  (coalesced, uint2 per chunk)
    for (int idx = tid; idx < nn * 12; idx += 512) {
        int j = idx / 12, c = idx % 12;
        int n = n0 + j;
        float di = dinv_l[j];
        const float4* xr = (const float4*)(x + (size_t)n * FP + c * 4);
        float4 a = xr[0];
        __half2 h0 = __floats2half2_rn(di * a.x, di * a.y);
        __half2 h1 = __floats2half2_rn(di * a.z, di * a.w);
        uint2 o;
        o.x = *(unsigned int*)&h0; o.y = *(unsigned int*)&h1;
        xs[(size_t)n * 12 + c] = o;
    }
}

// ---- pass 5: 12-lane/node gather, 8-wide MLP unroll, no barriers ----
// xagg[n] = fp16( dinv[n] * (xs[n] + sum ew_e * xs[src_e]) )
__global__ void __launch_bounds__(256) k_gather(const uint2* __restrict__ xs,
                                                const float* __restrict__ dinv,
                                                const int* __restrict__ offs,
                                                const unsigned long long* __restrict__ part,
                                                uint2* __restrict__ xagg2) {
    int t = blockIdx.x * 256 + threadIdx.x;
    if (t >= N_NODES * 12) return;
    int n = t / 12, c = t % 12;
    uint2 self = xs[(size_t)n * 12 + c];
    float2 f0 = __half22float2(*(__half2*)&self.x);
    float2 f1 = __half22float2(*(__half2*)&self.y);
    float a0 = f0.x, a1 = f0.y, a2 = f1.x, a3 = f1.y;
    int b = offs[n], e = offs[n + 1];
    int kk = b;
    for (; kk + 8 <= e; kk += 8) {
        unsigned long long p[8];
        uint2 v[8];
        #pragma unroll
        for (int u = 0; u < 8; u++) p[u] = part[kk + u];
        #pragma unroll
        for (int u = 0; u < 8; u++)
            v[u] = xs[(size_t)((unsigned int)p[u] & SRC_MASK) * 12 + c];
        #pragma unroll
        for (int u = 0; u < 8; u++) {
            float w = __uint_as_float((unsigned int)(p[u] >> 32));
            float2 e0 = __half22float2(*(__half2*)&v[u].x);
            float2 e1 = __half22float2(*(__half2*)&v[u].y);
            a0 += w * e0.x; a1 += w * e0.y; a2 += w * e1.x; a3 += w * e1.y;
        }
    }
    for (; kk + 4 <= e; kk += 4) {
        unsigned long long p[4];
        uint2 v[4];
        #pragma unroll
        for (int u = 0; u < 4; u++) p[u] = part[kk + u];
        #pragma unroll
        for (int u = 0; u < 4; u++)
            v[u] = xs[(size_t)((unsigned int)p[u] & SRC_MASK) * 12 + c];
        #pragma unroll
        for (int u = 0; u < 4; u++) {
            float w = __uint_as_float((unsigned int)(p[u] >> 32));
            float2 e0 = __half22float2(*(__half2*)&v[u].x);
            float2 e1 = __half22float2(*(__half2*)&v[u].y);
            a0 += w * e0.x; a1 += w * e0.y; a2 += w * e1.x; a3 += w * e1.y;
        }
    }
    for (; kk < e; kk++) {
        unsigned long long p = part[kk];
        float w = __uint_as_float((unsigned int)(p >> 32));
        uint2 v = xs[(size_t)((unsigned int)p & SRC_MASK) * 12 + c];
        float2 e0 = __half22float2(*(__half2*)&v.x);
        float2 e1 = __half22float2(*(__half2*)&v.y);
        a0 += w * e0.x; a1 += w * e0.y; a2 += w * e1.x; a3 += w * e1.y;
    }
    float di = dinv[n];
    __half2 o0 = __floats2half2_rn(di * a0, di * a1);
    __half2 o1 = __floats2half2_rn(di * a2, di * a3);
    uint2 o;
    o.x = *(unsigned int*)&o0; o.y = *(unsigned int*)&o1;
    xagg2[(size_t)n * 12 + c] = o;
}

// ---- pass 6: per-node fused epilogue (gates + attention + relu + linear) ----
// H0 == 0 => R gate dead; Z/Ht use only first F_OUT cols of lzW/lhW.
__global__ void k_node(const uint2* __restrict__ xagg2, const float* __restrict__ att,
                       const float* __restrict__ Wz, const float* __restrict__ bz,
                       const float* __restrict__ Wh, const float* __restrict__ bh,
                       const float* __restrict__ lzW, const float* __restrict__ lzb,
                       const float* __restrict__ lhW, const float* __restrict__ lhb,
                       const float* __restrict__ linW, const float* __restrict__ linb,
                       float* __restrict__ out) {
    int n = blockIdx.x * blockDim.x + threadIdx.x;
    if (n >= N_NODES) return;

    float a[PERIODS];
    float m = -1e30f;
    #pragma unroll
    for (int p = 0; p < PERIODS; p++) { a[p] = att[p]; m = fmaxf(m, a[p]); }
    float se = 0.f;
    #pragma unroll
    for (int p = 0; p < PERIODS; p++) { a[p] = __expf(a[p] - m); se += a[p]; }
    float inv = 1.f / se;
    #pragma unroll
    for (int p = 0; p < PERIODS; p++) a[p] *= inv;

    float row[FP];
    const uint2* xr = xagg2 + (size_t)n * 12;
    #pragma unroll
    for (int i = 0; i < 12; i++) {
        uint2 v = xr[i];
        float2 f0 = __half22float2(*(__half2*)&v.x);
        float2 f1 = __half22float2(*(__half2*)&v.y);
        row[4 * i] = f0.x; row[4 * i + 1] = f0.y;
        row[4 * i + 2] = f1.x; row[4 * i + 3] = f1.y;
    }

    float H[F_OUT];
    #pragma unroll
    for (int j = 0; j < F_OUT; j++) H[j] = 0.f;

    for (int p = 0; p < PERIODS; p++) {
        float gz[F_OUT], gh[F_OUT];
        #pragma unroll
        for (int j = 0; j < F_OUT; j++) { gz[j] = bz[j]; gh[j] = bh[j]; }
        #pragma unroll
        for (int f = 0; f < F_IN; f++) {
            float xv = row[f * PERIODS + p];
            #pragma unroll
            for (int j = 0; j < F_OUT; j++) {
                gz[j] += xv * Wz[f * F_OUT + j];
                gh[j] += xv * Wh[f * F_OUT + j];
            }
        }
        #pragma unroll
        for (int j = 0; j < F_OUT; j++) {
            float z = lzb[j], t2 = lhb[j];
            #pragma unroll
            for (int kk = 0; kk < F_OUT; kk++) {
                z  += gz[kk] * lzW[j * (2 * F_OUT) + kk];
                t2 += gh[kk] * lhW[j * (2 * F_OUT) + kk];
            }
            float Z = 1.f / (1.f + __expf(-z));
            H[j] += a[p] * (1.f - Z) * tanhf(t2);
        }
    }

    float* op = out + (size_t)n * PERIODS;
    #pragma unroll
    for (int q = 0; q < PERIODS; q++) {
        float acc = linb[q];
        #pragma unroll
        for (int j = 0; j < F_OUT; j++)
            acc += fmaxf(H[j], 0.f) * linW[q * F_OUT + j];
        op[q] = acc;
    }
}

extern "C" void kernel_launch(void* const* d_in, const int* in_sizes, int n_in,
                              void* d_out, int out_size, void* d_ws, size_t ws_size,
                              hipStream_t stream) {
    const float* x    = (const float*)d_in[0];
    const int*   ei   = (const int*)d_in[1];
    const float* ew   = (const float*)d_in[2];
    const float* att  = (const float*)d_in[3];
    const float* Wz   = (const float*)d_in[4];
    const float* bz   = (const float*)d_in[5];
    // d_in[6]=Wr, d_in[7]=br : dead (H0 == 0)
    const float* Wh   = (const float*)d_in[8];
    const float* bh   = (const float*)d_in[9];
    const float* lzW  = (const float*)d_in[10];
    const float* lzb  = (const float*)d_in[11];
    // d_in[12]=lrW, d_in[13]=lrb : dead
    const float* lhW  = (const float*)d_in[14];
    const float* lhb  = (const float*)d_in[15];
    const float* linW = (const float*)d_in[16];
    const float* linb = (const float*)d_in[17];
    float* out = (float*)d_out;

    // ws layout (~25 MB)
    unsigned long long* part = (unsigned long long*)d_ws;            // E * 8B (sorted in place)
    uint2* xs = (uint2*)(part + N_EDGES);                            // N*12 uint2 = 4.8 MB
    uint2* xagg2 = xs + (size_t)N_NODES * 12;                        // N*12 uint2 = 4.8 MB
    unsigned int* hist = (unsigned int*)(xagg2 + (size_t)N_NODES * 12); // NCHK*NBKT u32
    float* dinv = (float*)(hist + (size_t)NCHK * NBKT);              // N floats
    int*   offs = (int*)(dinv + N_NODES);                            // N+1 ints
    unsigned int* tot = (unsigned int*)(offs + N_NODES + 1);         // NBKT u32

    const int* srcp = ei;
    const int* dstp = ei + N_EDGES;

    k_hist<<<NCHK, 256, 0, stream>>>(dstp, hist);
    k_colscan<<<NBKT, 1024, 0, stream>>>(hist, tot);
    k_scatter<<<NCHK, 512, 0, stream>>>(srcp, dstp, ew, hist, tot, part);
    k_bucket<<<NBKT, 512, 0, stream>>>(part, tot, x, offs, dinv, xs);
    k_gather<<<(N_NODES * 12 + 255) / 256, 256, 0, stream>>>(xs, dinv, offs, part, xagg2);
    k_node<<<(N_NODES + 255) / 256, 256, 0, stream>>>(xagg2, att, Wz, bz, Wh, bh,
                                                      lzW, lzb, lhW, lhb, linW, linb, out);
}

// Round 15
// 217.276 us; speedup vs baseline: 1.4234x; 1.0145x over previous
//
#include <hip/hip_runtime.h>
#include <hip/hip_fp16.h>

#define N_NODES 50000
#define N_EDGES 1600000
#define F_IN 8
#define F_OUT 12
#define PERIODS 6
#define FP 48                      // F_IN * PERIODS
#define BKT_SH 7                   // 128 nodes per bucket
#define BKT_N 128
#define NBKT ((N_NODES + BKT_N - 1) / BKT_N)   // 391
#define CHK 2048
#define NCHK ((N_EDGES + CHK - 1) / CHK)       // 782
#define SEG_CAP 4736               // fixed per-bucket segment stride (mean 4092, +10 sigma)
#define SRC_MASK 0x1FFFFu          // src < 50000 < 2^17

// ---- pass 0: zero the 391 bucket cursors ----
__global__ void k_zero(unsigned int* __restrict__ cursor) {
    int i = threadIdx.x;
    if (i < NBKT) cursor[i] = 0u;
}

// ---- pass 1: fused histogram + reservation + scatter ----
// Fixed-stride segments: bucket b owns part[b*SEG_CAP ...]. Each block:
//   (1) LDS histogram of its 2048-edge chunk, per-edge rank kept in registers
//   (2) one global atomicAdd per non-empty (block,bucket) to reserve space
//   (3) scatter edges to reserved slots.  entry: hi32=ew bits, lo32=(d&127)<<24|src
__global__ void __launch_bounds__(512) k_scatter(const int* __restrict__ src,
                                                 const int* __restrict__ dst,
                                                 const float* __restrict__ ew,
                                                 unsigned int* __restrict__ cursor,
                                                 unsigned long long* __restrict__ part) {
    __shared__ unsigned int h[NBKT];
    __shared__ unsigned int gbase[NBKT];
    int tid = threadIdx.x, blk = blockIdx.x;
    for (int k = tid; k < NBKT; k += 512) h[k] = 0u;
    __syncthreads();
    int base = blk * CHK;
    int bv[4]; unsigned int lr[4], lo[4], hiw[4]; bool val[4];
    #pragma unroll
    for (int u = 0; u < 4; u++) {
        int e = base + u * 512 + tid;
        val[u] = (e < N_EDGES);
        if (val[u]) {
            int s = src[e], d = dst[e];
            int b = d >> BKT_SH;
            bv[u] = b;
            lr[u] = atomicAdd(&h[b], 1u);
            lo[u] = ((unsigned int)(d & (BKT_N - 1)) << 24) | (unsigned int)s;
            hiw[u] = __float_as_uint(ew[e]);
        }
    }
    __syncthreads();
    for (int k = tid; k < NBKT; k += 512) {
        unsigned int c = h[k];
        gbase[k] = c ? atomicAdd(&cursor[k], c) : 0u;
    }
    __syncthreads();
    #pragma unroll
    for (int u = 0; u < 4; u++) {
        if (!val[u]) continue;
        unsigned int off = gbase[bv[u]] + lr[u];
        if (off < SEG_CAP)  // 10-sigma margin; memory safety only
            part[(size_t)bv[u] * SEG_CAP + off] =
                ((unsigned long long)hiw[u] << 32) | lo[u];
    }
}

// ---- pass 2: per-bucket LDS counting sort + deg/dinv + fp16 xs, fused ----
__global__ void __launch_bounds__(512) k_bucket(unsigned long long* __restrict__ part,
                                                const unsigned int* __restrict__ cursor,
                                                const float* __restrict__ x,
                                                int2* __restrict__ offs2,
                                                float* __restrict__ dinv_g,
                                                uint2* __restrict__ xs) {
    __shared__ uint2 stage[SEG_CAP];
    __shared__ unsigned int cnt[BKT_N], cnt2[BKT_N], rowstart[BKT_N], sc[BKT_N];
    __shared__ float degf[BKT_N], dinv_l[BKT_N];
    int tid = threadIdx.x, k = blockIdx.x;
    unsigned int base = (unsigned int)k * SEG_CAP;
    unsigned int m = cursor[k];
    if (m > SEG_CAP) m = SEG_CAP;
    if (tid < BKT_N) { cnt[tid] = 0u; cnt2[tid] = 0u; degf[tid] = 1.0f; }  // self loop
    __syncthreads();
    for (unsigned int i = tid; i < m; i += 512) {
        unsigned long long p = part[base + i];
        unsigned int lo = (unsigned int)p;
        unsigned int hi = (unsigned int)(p >> 32);
        stage[i] = make_uint2(lo, hi);
        unsigned int j = (lo >> 24) & (BKT_N - 1);
        atomicAdd(&cnt[j], 1u);
        atomicAdd(&degf[j], __uint_as_float(hi));
    }
    __syncthreads();
    if (tid < BKT_N) sc[tid] = cnt[tid];
    __syncthreads();
    for (int off = 1; off < BKT_N; off <<= 1) {
        unsigned int u = (tid >= (unsigned)off && tid < BKT_N) ? sc[tid - off] : 0u;
        __syncthreads();
        if (tid < BKT_N) sc[tid] += u;
        __syncthreads();
    }
    if (tid < BKT_N) rowstart[tid] = sc[tid] - cnt[tid];
    __syncthreads();

    int n0 = k * BKT_N;
    int nn = N_NODES - n0; if (nn > BKT_N) nn = BKT_N;

    if (tid < BKT_N) {
        float dv = rsqrtf(degf[tid]);
        dinv_l[tid] = dv;
        if (tid < nn) {
            dinv_g[n0 + tid] = dv;
            offs2[n0 + tid] = make_int2((int)(base + rowstart[tid]),
                                        (int)(base + sc[tid]));
        }
    }

    // sorted in-place write (reads from LDS stage — no hazard)
    for (unsigned int i = tid; i < m; i += 512) {
        uint2 vv = stage[i];
        unsigned int j = (vv.x >> 24) & (BKT_N - 1);
        unsigned int r = atomicAdd(&cnt2[j], 1u);
        part[base + rowstart[j] + r] = ((unsigned long long)vv.y << 32) | vv.x;
    }
    __syncthreads();

    // xs[n*12+c] = fp16(dinv[n] * x[n, 4c..4c+3])  (coalesced, uint2 per chunk)
    for (int idx = tid; idx < nn * 12; idx += 512) {
        int j = idx / 12, c = idx % 12;
        int n = n0 + j;
        float di = dinv_l[j];
        const float4* xr = (const float4*)(x + (size_t)n * FP + c * 4);
        float4 a = xr[0];
        __half2 h0 = __floats2half2_rn(di * a.x, di * a.y);
        __half2 h1 = __floats2half2_rn(di * a.z, di * a.w);
        uint2 o;
        o.x = *(unsigned int*)&h0; o.y = *(unsigned int*)&h1;
        xs[(size_t)n * 12 + c] = o;
    }
}

// ---- pass 3: 12-lane/node gather, 8-wide MLP unroll, no barriers ----
// xagg[n] = fp16( dinv[n] * (xs[n] + sum ew_e * xs[src_e]) )
__global__ void __launch_bounds__(256) k_gather(const uint2* __restrict__ xs,
                                                const float* __restrict__ dinv,
                                                const int2* __restrict__ offs2,
                                                const unsigned long long* __restrict__ part,
                                                uint2* __restrict__ xagg2) {
    int t = blockIdx.x * 256 + threadIdx.x;
    if (t >= N_NODES * 12) return;
    int n = t / 12, c = t % 12;
    uint2 self = xs[(size_t)n * 12 + c];
    float2 f0 = __half22float2(*(__half2*)&self.x);
    float2 f1 = __half22float2(*(__half2*)&self.y);
    float a0 = f0.x, a1 = f0.y, a2 = f1.x, a3 = f1.y;
    int2 oe = offs2[n];
    int b = oe.x, e = oe.y;
    int kk = b;
    for (; kk + 8 <= e; kk += 8) {
        unsigned long long p[8];
        uint2 v[8];
        #pragma unroll
        for (int u = 0; u < 8; u++) p[u] = part[kk + u];
        #pragma unroll
        for (int u = 0; u < 8; u++)
            v[u] = xs[(size_t)((unsigned int)p[u] & SRC_MASK) * 12 + c];
        #pragma unroll
        for (int u = 0; u < 8; u++) {
            float w = __uint_as_float((unsigned int)(p[u] >> 32));
            float2 e0 = __half22float2(*(__half2*)&v[u].x);
            float2 e1 = __half22float2(*(__half2*)&v[u].y);
            a0 += w * e0.x; a1 += w * e0.y; a2 += w * e1.x; a3 += w * e1.y;
        }
    }
    for (; kk + 4 <= e; kk += 4) {
        unsigned long long p[4];
        uint2 v[4];
        #pragma unroll
        for (int u = 0; u < 4; u++) p[u] = part[kk + u];
        #pragma unroll
        for (int u = 0; u < 4; u++)
            v[u] = xs[(size_t)((unsigned int)p[u] & SRC_MASK) * 12 + c];
        #pragma unroll
        for (int u = 0; u < 4; u++) {
            float w = __uint_as_float((unsigned int)(p[u] >> 32));
            float2 e0 = __half22float2(*(__half2*)&v[u].x);
            float2 e1 = __half22float2(*(__half2*)&v[u].y);
            a0 += w * e0.x; a1 += w * e0.y; a2 += w * e1.x; a3 += w * e1.y;
        }
    }
    for (; kk < e; kk++) {
        unsigned long long p = part[kk];
        float w = __uint_as_float((unsigned int)(p >> 32));
        uint2 v = xs[(size_t)((unsigned int)p & SRC_MASK) * 12 + c];
        float2 e0 = __half22float2(*(__half2*)&v.x);
        float2 e1 = __half22float2(*(__half2*)&v.y);
        a0 += w * e0.x; a1 += w * e0.y; a2 += w * e1.x; a3 += w * e1.y;
    }
    float di = dinv[n];
    __half2 o0 = __floats2half2_rn(di * a0, di * a1);
    __half2 o1 = __floats2half2_rn(di * a2, di * a3);
    uint2 o;
    o.x = *(unsigned int*)&o0; o.y = *(unsigned int*)&o1;
    xagg2[(size_t)n * 12 + c] = o;
}

// ---- pass 4: per-node fused epilogue (gates + attention + relu + linear) ----
// H0 == 0 => R gate dead; Z/Ht use only first F_OUT cols of lzW/lhW.
__global__ void k_node(const uint2* __restrict__ xagg2, const float* __restrict__ att,
                       const float* __restrict__ Wz, const float* __restrict__ bz,
                       const float* __restrict__ Wh, const float* __restrict__ bh,
                       const float* __restrict__ lzW, const float* __restrict__ lzb,
                       const float* __restrict__ lhW, const float* __restrict__ lhb,
                       const float* __restrict__ linW, const float* __restrict__ linb,
                       float* __restrict__ out) {
    int n = blockIdx.x * blockDim.x + threadIdx.x;
    if (n >= N_NODES) return;

    float a[PERIODS];
    float m = -1e30f;
    #pragma unroll
    for (int p = 0; p < PERIODS; p++) { a[p] = att[p]; m = fmaxf(m, a[p]); }
    float se = 0.f;
    #pragma unroll
    for (int p = 0; p < PERIODS; p++) { a[p] = __expf(a[p] - m); se += a[p]; }
    float inv = 1.f / se;
    #pragma unroll
    for (int p = 0; p < PERIODS; p++) a[p] *= inv;

    float row[FP];
    const uint2* xr = xagg2 + (size_t)n * 12;
    #pragma unroll
    for (int i = 0; i < 12; i++) {
        uint2 v = xr[i];
        float2 f0 = __half22float2(*(__half2*)&v.x);
        float2 f1 = __half22float2(*(__half2*)&v.y);
        row[4 * i] = f0.x; row[4 * i + 1] = f0.y;
        row[4 * i + 2] = f1.x; row[4 * i + 3] = f1.y;
    }

    float H[F_OUT];
    #pragma unroll
    for (int j = 0; j < F_OUT; j++) H[j] = 0.f;

    for (int p = 0; p < PERIODS; p++) {
        float gz[F_OUT], gh[F_OUT];
        #pragma unroll
        for (int j = 0; j < F_OUT; j++) { gz[j] = bz[j]; gh[j] = bh[j]; }
        #pragma unroll
        for (int f = 0; f < F_IN; f++) {
            float xv = row[f * PERIODS + p];
            #pragma unroll
            for (int j = 0; j < F_OUT; j++) {
                gz[j] += xv * Wz[f * F_OUT + j];
                gh[j] += xv * Wh[f * F_OUT + j];
            }
        }
        #pragma unroll
        for (int j = 0; j < F_OUT; j++) {
            float z = lzb[j], t2 = lhb[j];
            #pragma unroll
            for (int kk = 0; kk < F_OUT; kk++) {
                z  += gz[kk] * lzW[j * (2 * F_OUT) + kk];
                t2 += gh[kk] * lhW[j * (2 * F_OUT) + kk];
            }
            float Z = 1.f / (1.f + __expf(-z));
            H[j] += a[p] * (1.f - Z) * tanhf(t2);
        }
    }

    float* op = out + (size_t)n * PERIODS;
    #pragma unroll
    for (int q = 0; q < PERIODS; q++) {
        float acc = linb[q];
        #pragma unroll
        for (int j = 0; j < F_OUT; j++)
            acc += fmaxf(H[j], 0.f) * linW[q * F_OUT + j];
        op[q] = acc;
    }
}

extern "C" void kernel_launch(void* const* d_in, const int* in_sizes, int n_in,
                              void* d_out, int out_size, void* d_ws, size_t ws_size,
                              hipStream_t stream) {
    const float* x    = (const float*)d_in[0];
    const int*   ei   = (const int*)d_in[1];
    const float* ew   = (const float*)d_in[2];
    const float* att  = (const float*)d_in[3];
    const float* Wz   = (const float*)d_in[4];
    const float* bz   = (const float*)d_in[5];
    // d_in[6]=Wr, d_in[7]=br : dead (H0 == 0)
    const float* Wh   = (const float*)d_in[8];
    const float* bh   = (const float*)d_in[9];
    const float* lzW  = (const float*)d_in[10];
    const float* lzb  = (const float*)d_in[11];
    // d_in[12]=lrW, d_in[13]=lrb : dead
    const float* lhW  = (const float*)d_in[14];
    const float* lhb  = (const float*)d_in[15];
    const float* linW = (const float*)d_in[16];
    const float* linb = (const float*)d_in[17];
    float* out = (float*)d_out;

    // ws layout (~25 MB): fixed-stride part, xs, xagg, dinv, offs2, cursor
    unsigned long long* part = (unsigned long long*)d_ws;        // NBKT*SEG_CAP * 8B
    uint2* xs = (uint2*)(part + (size_t)NBKT * SEG_CAP);         // N*12 uint2 = 4.8 MB
    uint2* xagg2 = xs + (size_t)N_NODES * 12;                    // N*12 uint2 = 4.8 MB
    float* dinv = (float*)(xagg2 + (size_t)N_NODES * 12);        // N floats
    int2*  offs2 = (int2*)(dinv + N_NODES);                      // N int2
    unsigned int* cursor = (unsigned int*)(offs2 + N_NODES);     // NBKT u32

    const int* srcp = ei;
    const int* dstp = ei + N_EDGES;

    k_zero<<<1, 512, 0, stream>>>(cursor);
    k_scatter<<<NCHK, 512, 0, stream>>>(srcp, dstp, ew, cursor, part);
    k_bucket<<<NBKT, 512, 0, stream>>>(part, cursor, x, offs2, dinv, xs);
    k_gather<<<(N_NODES * 12 + 255) / 256, 256, 0, stream>>>(xs, dinv, offs2, part, xagg2);
    k_node<<<(N_NODES + 255) / 256, 256, 0, stream>>>(xagg2, att, Wz, bz, Wh, bh,
                                                      lzW, lzb, lhW, lhb, linW, linb, out);
}

// Round 16
// 211.966 us; speedup vs baseline: 1.4590x; 1.0251x over previous
//
#include <hip/hip_runtime.h>
#include <hip/hip_fp16.h>

#define N_NODES 50000
#define N_EDGES 1600000
#define F_IN 8
#define F_OUT 12
#define PERIODS 6
#define FP 48                      // F_IN * PERIODS
#define BKT_SH 7                   // 128 nodes per bucket
#define BKT_N 128
#define NBKT ((N_NODES + BKT_N - 1) / BKT_N)   // 391
#define CHK 2048
#define NCHK ((N_EDGES + CHK - 1) / CHK)       // 782
#define SEG_CAP 4736               // fixed per-bucket segment stride (mean 4092, +10 sigma)

// ---- pass 0: zero the 391 bucket cursors ----
__global__ void k_zero(unsigned int* __restrict__ cursor) {
    int i = threadIdx.x;
    if (i < NBKT) cursor[i] = 0u;
}

// ---- pass 1: fused histogram + reservation + scatter ----
// Fixed-stride segments: bucket b owns part[b*SEG_CAP ...]. Each block:
//   (1) LDS histogram of its 2048-edge chunk, per-edge rank kept in registers
//   (2) one global atomicAdd per non-empty (block,bucket) to reserve space
//   (3) scatter edges to reserved slots.  entry: hi32=ew bits, lo32=(d&127)<<24|src
__global__ void __launch_bounds__(512) k_scatter(const int* __restrict__ src,
                                                 const int* __restrict__ dst,
                                                 const float* __restrict__ ew,
                                                 unsigned int* __restrict__ cursor,
                                                 unsigned long long* __restrict__ part) {
    __shared__ unsigned int h[NBKT];
    __shared__ unsigned int gbase[NBKT];
    int tid = threadIdx.x, blk = blockIdx.x;
    for (int k = tid; k < NBKT; k += 512) h[k] = 0u;
    __syncthreads();
    int base = blk * CHK;
    int bv[4]; unsigned int lr[4], lo[4], hiw[4]; bool val[4];
    #pragma unroll
    for (int u = 0; u < 4; u++) {
        int e = base + u * 512 + tid;
        val[u] = (e < N_EDGES);
        if (val[u]) {
            int s = src[e], d = dst[e];
            int b = d >> BKT_SH;
            bv[u] = b;
            lr[u] = atomicAdd(&h[b], 1u);
            lo[u] = ((unsigned int)(d & (BKT_N - 1)) << 24) | (unsigned int)s;
            hiw[u] = __float_as_uint(ew[e]);
        }
    }
    __syncthreads();
    for (int k = tid; k < NBKT; k += 512) {
        unsigned int c = h[k];
        gbase[k] = c ? atomicAdd(&cursor[k], c) : 0u;
    }
    __syncthreads();
    #pragma unroll
    for (int u = 0; u < 4; u++) {
        if (!val[u]) continue;
        unsigned int off = gbase[bv[u]] + lr[u];
        if (off < SEG_CAP)  // 10-sigma margin; memory safety only
            part[(size_t)bv[u] * SEG_CAP + off] =
                ((unsigned long long)hiw[u] << 32) | lo[u];
    }
}

// ---- pass 2: per-bucket LDS counting sort + deg/dinv + fp16 xs + 4B csr ----
// csr4 entry: (fp16(ew) << 16) | src  (src < 50000 < 2^16)
__global__ void __launch_bounds__(512) k_bucket(const unsigned long long* __restrict__ part,
                                                const unsigned int* __restrict__ cursor,
                                                const float* __restrict__ x,
                                                int2* __restrict__ offs2,
                                                float* __restrict__ dinv_g,
                                                uint2* __restrict__ xs,
                                                unsigned int* __restrict__ csr4) {
    __shared__ uint2 stage[SEG_CAP];
    __shared__ unsigned int cnt[BKT_N], cnt2[BKT_N], rowstart[BKT_N], sc[BKT_N];
    __shared__ float degf[BKT_N], dinv_l[BKT_N];
    int tid = threadIdx.x, k = blockIdx.x;
    unsigned int base = (unsigned int)k * SEG_CAP;
    unsigned int m = cursor[k];
    if (m > SEG_CAP) m = SEG_CAP;
    if (tid < BKT_N) { cnt[tid] = 0u; cnt2[tid] = 0u; degf[tid] = 1.0f; }  // self loop
    __syncthreads();
    for (unsigned int i = tid; i < m; i += 512) {
        unsigned long long p = part[base + i];
        unsigned int lo = (unsigned int)p;
        unsigned int hi = (unsigned int)(p >> 32);
        stage[i] = make_uint2(lo, hi);
        unsigned int j = (lo >> 24) & (BKT_N - 1);
        atomicAdd(&cnt[j], 1u);
        atomicAdd(&degf[j], __uint_as_float(hi));   // full fp32 weight for deg
    }
    __syncthreads();
    if (tid < BKT_N) sc[tid] = cnt[tid];
    __syncthreads();
    for (int off = 1; off < BKT_N; off <<= 1) {
        unsigned int u = (tid >= (unsigned)off && tid < BKT_N) ? sc[tid - off] : 0u;
        __syncthreads();
        if (tid < BKT_N) sc[tid] += u;
        __syncthreads();
    }
    if (tid < BKT_N) rowstart[tid] = sc[tid] - cnt[tid];
    __syncthreads();

    int n0 = k * BKT_N;
    int nn = N_NODES - n0; if (nn > BKT_N) nn = BKT_N;

    if (tid < BKT_N) {
        float dv = rsqrtf(degf[tid]);
        dinv_l[tid] = dv;
        if (tid < nn) {
            dinv_g[n0 + tid] = dv;
            offs2[n0 + tid] = make_int2((int)(base + rowstart[tid]),
                                        (int)(base + sc[tid]));
        }
    }

    // sorted write as compact 4B entries (reads from LDS stage — no hazard)
    for (unsigned int i = tid; i < m; i += 512) {
        uint2 vv = stage[i];
        unsigned int j = (vv.x >> 24) & (BKT_N - 1);
        unsigned int r = atomicAdd(&cnt2[j], 1u);
        __half hw = __float2half(__uint_as_float(vv.y));
        unsigned int entry = ((unsigned int)__half_as_ushort(hw) << 16) |
                             (vv.x & 0xFFFFu);
        csr4[base + rowstart[j] + r] = entry;
    }
    __syncthreads();

    // xs[n*12+c] = fp16(dinv[n] * x[n, 4c..4c+3])  (coalesced, uint2 per chunk)
    for (int idx = tid; idx < nn * 12; idx += 512) {
        int j = idx / 12, c = idx % 12;
        int n = n0 + j;
        float di = dinv_l[j];
        const float4* xr = (const float4*)(x + (size_t)n * FP + c * 4);
        float4 a = xr[0];
        __half2 h0 = __floats2half2_rn(di * a.x, di * a.y);
        __half2 h1 = __floats2half2_rn(di * a.z, di * a.w);
        uint2 o;
        o.x = *(unsigned int*)&h0; o.y = *(unsigned int*)&h1;
        xs[(size_t)n * 12 + c] = o;
    }
}

// ---- pass 3: 12-lane/node gather over 4B csr, 8-wide MLP unroll, no barriers ----
// xagg[n] = fp16( dinv[n] * (xs[n] + sum ew_e * xs[src_e]) )
__global__ void __launch_bounds__(256) k_gather(const uint2* __restrict__ xs,
                                                const float* __restrict__ dinv,
                                                const int2* __restrict__ offs2,
                                                const unsigned int* __restrict__ csr4,
                                                uint2* __restrict__ xagg2) {
    int t = blockIdx.x * 256 + threadIdx.x;
    if (t >= N_NODES * 12) return;
    int n = t / 12, c = t % 12;
    uint2 self = xs[(size_t)n * 12 + c];
    float2 f0 = __half22float2(*(__half2*)&self.x);
    float2 f1 = __half22float2(*(__half2*)&self.y);
    float a0 = f0.x, a1 = f0.y, a2 = f1.x, a3 = f1.y;
    int2 oe = offs2[n];
    int b = oe.x, e = oe.y;
    int kk = b;
    for (; kk + 8 <= e; kk += 8) {
        unsigned int p[8];
        uint2 v[8];
        #pragma unroll
        for (int u = 0; u < 8; u++) p[u] = csr4[kk + u];
        #pragma unroll
        for (int u = 0; u < 8; u++)
            v[u] = xs[(size_t)(p[u] & 0xFFFFu) * 12 + c];
        #pragma unroll
        for (int u = 0; u < 8; u++) {
            float w = __half2float(__ushort_as_half((unsigned short)(p[u] >> 16)));
            float2 e0 = __half22float2(*(__half2*)&v[u].x);
            float2 e1 = __half22float2(*(__half2*)&v[u].y);
            a0 += w * e0.x; a1 += w * e0.y; a2 += w * e1.x; a3 += w * e1.y;
        }
    }
    for (; kk + 4 <= e; kk += 4) {
        unsigned int p[4];
        uint2 v[4];
        #pragma unroll
        for (int u = 0; u < 4; u++) p[u] = csr4[kk + u];
        #pragma unroll
        for (int u = 0; u < 4; u++)
            v[u] = xs[(size_t)(p[u] & 0xFFFFu) * 12 + c];
        #pragma unroll
        for (int u = 0; u < 4; u++) {
            float w = __half2float(__ushort_as_half((unsigned short)(p[u] >> 16)));
            float2 e0 = __half22float2(*(__half2*)&v[u].x);
            float2 e1 = __half22float2(*(__half2*)&v[u].y);
            a0 += w * e0.x; a1 += w * e0.y; a2 += w * e1.x; a3 += w * e1.y;
        }
    }
    for (; kk < e; kk++) {
        unsigned int p = csr4[kk];
        float w = __half2float(__ushort_as_half((unsigned short)(p >> 16)));
        uint2 v = xs[(size_t)(p & 0xFFFFu) * 12 + c];
        float2 e0 = __half22float2(*(__half2*)&v.x);
        float2 e1 = __half22float2(*(__half2*)&v.y);
        a0 += w * e0.x; a1 += w * e0.y; a2 += w * e1.x; a3 += w * e1.y;
    }
    float di = dinv[n];
    __half2 o0 = __floats2half2_rn(di * a0, di * a1);
    __half2 o1 = __floats2half2_rn(di * a2, di * a3);
    uint2 o;
    o.x = *(unsigned int*)&o0; o.y = *(unsigned int*)&o1;
    xagg2[(size_t)n * 12 + c] = o;
}

// ---- pass 4: per-node fused epilogue (gates + attention + relu + linear) ----
// H0 == 0 => R gate dead; Z/Ht use only first F_OUT cols of lzW/lhW.
__global__ void k_node(const uint2* __restrict__ xagg2, const float* __restrict__ att,
                       const float* __restrict__ Wz, const float* __restrict__ bz,
                       const float* __restrict__ Wh, const float* __restrict__ bh,
                       const float* __restrict__ lzW, const float* __restrict__ lzb,
                       const float* __restrict__ lhW, const float* __restrict__ lhb,
                       const float* __restrict__ linW, const float* __restrict__ linb,
                       float* __restrict__ out) {
    int n = blockIdx.x * blockDim.x + threadIdx.x;
    if (n >= N_NODES) return;

    float a[PERIODS];
    float m = -1e30f;
    #pragma unroll
    for (int p = 0; p < PERIODS; p++) { a[p] = att[p]; m = fmaxf(m, a[p]); }
    float se = 0.f;
    #pragma unroll
    for (int p = 0; p < PERIODS; p++) { a[p] = __expf(a[p] - m); se += a[p]; }
    float inv = 1.f / se;
    #pragma unroll
    for (int p = 0; p < PERIODS; p++) a[p] *= inv;

    float row[FP];
    const uint2* xr = xagg2 + (size_t)n * 12;
    #pragma unroll
    for (int i = 0; i < 12; i++) {
        uint2 v = xr[i];
        float2 f0 = __half22float2(*(__half2*)&v.x);
        float2 f1 = __half22float2(*(__half2*)&v.y);
        row[4 * i] = f0.x; row[4 * i + 1] = f0.y;
        row[4 * i + 2] = f1.x; row[4 * i + 3] = f1.y;
    }

    float H[F_OUT];
    #pragma unroll
    for (int j = 0; j < F_OUT; j++) H[j] = 0.f;

    for (int p = 0; p < PERIODS; p++) {
        float gz[F_OUT], gh[F_OUT];
        #pragma unroll
        for (int j = 0; j < F_OUT; j++) { gz[j] = bz[j]; gh[j] = bh[j]; }
        #pragma unroll
        for (int f = 0; f < F_IN; f++) {
            float xv = row[f * PERIODS + p];
            #pragma unroll
            for (int j = 0; j < F_OUT; j++) {
                gz[j] += xv * Wz[f * F_OUT + j];
                gh[j] += xv * Wh[f * F_OUT + j];
            }
        }
        #pragma unroll
        for (int j = 0; j < F_OUT; j++) {
            float z = lzb[j], t2 = lhb[j];
            #pragma unroll
            for (int kk = 0; kk < F_OUT; kk++) {
                z  += gz[kk] * lzW[j * (2 * F_OUT) + kk];
                t2 += gh[kk] * lhW[j * (2 * F_OUT) + kk];
            }
            float Z = 1.f / (1.f + __expf(-z));
            H[j] += a[p] * (1.f - Z) * tanhf(t2);
        }
    }

    float* op = out + (size_t)n * PERIODS;
    #pragma unroll
    for (int q = 0; q < PERIODS; q++) {
        float acc = linb[q];
        #pragma unroll
        for (int j = 0; j < F_OUT; j++)
            acc += fmaxf(H[j], 0.f) * linW[q * F_OUT + j];
        op[q] = acc;
    }
}

extern "C" void kernel_launch(void* const* d_in, const int* in_sizes, int n_in,
                              void* d_out, int out_size, void* d_ws, size_t ws_size,
                              hipStream_t stream) {
    const float* x    = (const float*)d_in[0];
    const int*   ei   = (const int*)d_in[1];
    const float* ew   = (const float*)d_in[2];
    const float* att  = (const float*)d_in[3];
    const float* Wz   = (const float*)d_in[4];
    const float* bz   = (const float*)d_in[5];
    // d_in[6]=Wr, d_in[7]=br : dead (H0 == 0)
    const float* Wh   = (const float*)d_in[8];
    const float* bh   = (const float*)d_in[9];
    const float* lzW  = (const float*)d_in[10];
    const float* lzb  = (const float*)d_in[11];
    // d_in[12]=lrW, d_in[13]=lrb : dead
    const float* lhW  = (const float*)d_in[14];
    const float* lhb  = (const float*)d_in[15];
    const float* linW = (const float*)d_in[16];
    const float* linb = (const float*)d_in[17];
    float* out = (float*)d_out;

    // ws layout (~33 MB): fixed-stride part (8B), csr4 (4B), xs, xagg, dinv, offs2, cursor
    unsigned long long* part = (unsigned long long*)d_ws;        // NBKT*SEG_CAP * 8B
    unsigned int* csr4 = (unsigned int*)(part + (size_t)NBKT * SEG_CAP); // NBKT*SEG_CAP * 4B
    uint2* xs = (uint2*)(csr4 + (size_t)NBKT * SEG_CAP);         // N*12 uint2 = 4.8 MB
    uint2* xagg2 = xs + (size_t)N_NODES * 12;                    // N*12 uint2 = 4.8 MB
    float* dinv = (float*)(xagg2 + (size_t)N_NODES * 12);        // N floats
    int2*  offs2 = (int2*)(dinv + N_NODES);                      // N int2
    unsigned int* cursor = (unsigned int*)(offs2 + N_NODES);     // NBKT u32

    const int* srcp = ei;
    const int* dstp = ei + N_EDGES;

    k_zero<<<1, 512, 0, stream>>>(cursor);
    k_scatter<<<NCHK, 512, 0, stream>>>(srcp, dstp, ew, cursor, part);
    k_bucket<<<NBKT, 512, 0, stream>>>(part, cursor, x, offs2, dinv, xs, csr4);
    k_gather<<<(N_NODES * 12 + 255) / 256, 256, 0, stream>>>(xs, dinv, offs2, csr4, xagg2);
    k_node<<<(N_NODES + 255) / 256, 256, 0, stream>>>(xagg2, att, Wz, bz, Wh, bh,
                                                      lzW, lzb, lhW, lhb, linW, linb, out);
}